// Round 1
// baseline (1226.101 us; speedup 1.0000x reference)
//
#include <hip/hip_runtime.h>
#include <cstdint>

// Shapes (fixed by the problem): B=2, C=64, G=4 -> CG=256, DQK=8, L=64*64=4096
constexpr int Bc  = 2;
constexpr int CGc = 256;
constexpr int Dc  = 8;
constexpr int Lc  = 4096;

// ---------------------------------------------------------------------------
// Phase 0: transpose wv (2,CG,CG) [o][cin] -> wvT [cin][o] so the V-projection
// inner loop reads weights coalesced across threads (thread = out-channel).
// ---------------------------------------------------------------------------
__global__ __launch_bounds__(256) void wv_transpose(const float* __restrict__ wv,
                                                    float* __restrict__ wvT) {
  const int i    = blockIdx.x * 256 + threadIdx.x;  // over 2*256*256 = 131072
  const int comp = i >> 16;
  const int rem  = i & 65535;
  const int cin  = rem >> 8;
  const int c    = rem & 255;
  wvT[i] = wv[(size_t)(comp * CGc + c) * CGc + cin];
}

// ---------------------------------------------------------------------------
// Phase 1: complex Q/K projections. q[b][m][0..7]=qr, [8..15]=qi (same for k).
// grid (L/256, B, 2): z=0 -> Q, z=1 -> K. Thread = one spatial position m.
// x layout: x[comp][b][cin][l], coalesced over m across lanes.
// ---------------------------------------------------------------------------
__global__ __launch_bounds__(256) void qk_proj(const float* __restrict__ x,
                                               const float* __restrict__ wq,
                                               const float* __restrict__ wk,
                                               float* __restrict__ qout,
                                               float* __restrict__ kout) {
  __shared__ float ws[2 * Dc * CGc];  // 16 KB: [comp][d][cin]
  const int tid = threadIdx.x;
  const int b   = blockIdx.y;
  const int z   = blockIdx.z;
  const float* w = z ? wk : wq;
  float* o       = z ? kout : qout;
  for (int i = tid; i < 2 * Dc * CGc; i += 256) ws[i] = w[i];
  __syncthreads();
  const int m = blockIdx.x * 256 + tid;
  float ar_acc[Dc] = {}, ai_acc[Dc] = {};
  const float* xr = x + ((size_t)(0 * Bc + b) * CGc) * Lc + m;
  const float* xi = x + ((size_t)(1 * Bc + b) * CGc) * Lc + m;
  for (int c = 0; c < CGc; ++c) {
    const float vr = xr[(size_t)c * Lc];
    const float vi = xi[(size_t)c * Lc];
#pragma unroll
    for (int d = 0; d < Dc; ++d) {
      const float wr = ws[d * CGc + c];
      const float wi = ws[(Dc + d) * CGc + c];
      ar_acc[d] += wr * vr - wi * vi;
      ai_acc[d] += wr * vi + wi * vr;
    }
  }
  float* op = o + ((size_t)b * Lc + m) * 16;
#pragma unroll
  for (int d = 0; d < Dc; ++d) {
    op[d]     = ar_acc[d];
    op[8 + d] = ai_acc[d];
  }
}

// ---------------------------------------------------------------------------
// Phase 2: complex V projection, stored L-MAJOR: vT[b][l][cc], cc=comp*256+c.
// This makes the attention PV loop's loads coalesced.
// grid (L/16, B); thread = out-channel c, 16 l's per block staged in LDS.
// ---------------------------------------------------------------------------
__global__ __launch_bounds__(256) void v_proj(const float* __restrict__ x,
                                              const float* __restrict__ wvT,
                                              float* __restrict__ vT) {
  constexpr int TL = 16;
  __shared__ float xs[2 * CGc * TL];  // 32 KB: [comp][cin][l]
  const int tid = threadIdx.x;
  const int b   = blockIdx.y;
  const int l0  = blockIdx.x * TL;
  for (int i = tid; i < 2 * CGc * TL; i += 256) {
    const int comp = i / (CGc * TL);
    const int rem  = i - comp * CGc * TL;
    const int cin  = rem >> 4;
    const int l    = rem & 15;
    xs[i] = x[((size_t)(comp * Bc + b) * CGc + cin) * Lc + l0 + l];
  }
  __syncthreads();
  float accr[TL] = {}, acci[TL] = {};
  const int c = tid;
  for (int cin = 0; cin < CGc; ++cin) {
    const float wr = wvT[(size_t)cin * CGc + c];                    // comp 0, coalesced
    const float wi = wvT[(size_t)(CGc + cin) * CGc + c];            // comp 1
    const float* xr = &xs[cin * TL];
    const float* xi = &xs[(CGc + cin) * TL];
#pragma unroll
    for (int l = 0; l < TL; ++l) {
      accr[l] += wr * xr[l] - wi * xi[l];
      acci[l] += wr * xi[l] + wi * xr[l];
    }
  }
#pragma unroll
  for (int l = 0; l < TL; ++l) {
    float* row = vT + ((size_t)b * Lc + l0 + l) * (2 * CGc);
    row[c]       = accr[l];
    row[CGc + c] = acci[l];
  }
}

// ---------------------------------------------------------------------------
// Phase 3: per-row softmax stats over energies E[b,m,l] = |q(m) . k(l)|^2.
// Online max/sum per thread, then block tree-combine. Stores M and 1/S.
// grid (L/8, B); 8 query rows per block.
// ---------------------------------------------------------------------------
__global__ __launch_bounds__(256) void softmax_stats(const float* __restrict__ q,
                                                     const float* __restrict__ k,
                                                     float* __restrict__ Mrow,
                                                     float* __restrict__ Sinv) {
  constexpr int TM = 8;
  __shared__ float qs[TM * 16];
  __shared__ float redm[256];
  __shared__ float reds[256];
  const int tid = threadIdx.x;
  const int b   = blockIdx.y;
  const int m0  = blockIdx.x * TM;
  if (tid < TM * 16) qs[tid] = q[((size_t)b * Lc + m0) * 16 + tid];
  __syncthreads();
  float mloc[TM], sloc[TM];
#pragma unroll
  for (int j = 0; j < TM; ++j) { mloc[j] = -1e30f; sloc[j] = 0.f; }
  for (int l = tid; l < Lc; l += 256) {
    const float* kp = k + ((size_t)b * Lc + l) * 16;
    float k0[16];
#pragma unroll
    for (int t = 0; t < 16; ++t) k0[t] = kp[t];
#pragma unroll
    for (int j = 0; j < TM; ++j) {
      float er = 0.f, ei = 0.f;
#pragma unroll
      for (int d = 0; d < 8; ++d) {
        const float a = qs[j * 16 + d], bb = qs[j * 16 + 8 + d];
        const float cc = k0[d], dd = k0[8 + d];
        er += a * cc - bb * dd;
        ei += a * dd + bb * cc;
      }
      const float e = er * er + ei * ei;
      if (e > mloc[j]) {
        sloc[j] = sloc[j] * expf(mloc[j] - e) + 1.f;
        mloc[j] = e;
      } else {
        sloc[j] += expf(e - mloc[j]);
      }
    }
  }
  for (int j = 0; j < TM; ++j) {
    redm[tid] = mloc[j];
    reds[tid] = sloc[j];
    __syncthreads();
    for (int off = 128; off > 0; off >>= 1) {
      if (tid < off) {
        const float m1 = redm[tid], m2 = redm[tid + off];
        const float s1 = reds[tid], s2 = reds[tid + off];
        const float mm = fmaxf(m1, m2);
        redm[tid] = mm;
        reds[tid] = s1 * expf(m1 - mm) + s2 * expf(m2 - mm);
      }
      __syncthreads();
    }
    if (tid == 0) {
      Mrow[(size_t)b * Lc + m0 + j] = redm[0];
      Sinv[(size_t)b * Lc + m0 + j] = 1.f / reds[0];
    }
    __syncthreads();
  }
}

// ---------------------------------------------------------------------------
// Phase 4: out[b,cc,m] = gamma * sum_l att[m,l]*v[cc,l] + x. Flash second pass:
// recompute E, w = exp(E-M)*Sinv staged in padded LDS (pad 17 -> only 2-way
// bank aliasing on the write = free), then coalesced PV accumulate.
// grid (L/16, B); thread = channel c (both comps), 16 queries per block.
// ---------------------------------------------------------------------------
__global__ __launch_bounds__(256) void attn_out(const float* __restrict__ q,
                                                const float* __restrict__ k,
                                                const float* __restrict__ vT,
                                                const float* __restrict__ Mrow,
                                                const float* __restrict__ Sinv,
                                                const float* __restrict__ x,
                                                const float* __restrict__ gamma,
                                                float* __restrict__ out) {
  constexpr int TM = 16, TL = 64, WP = TM + 1;
  __shared__ float qs[TM * 16];
  __shared__ float Ms[TM], Ss[TM];
  __shared__ float wls[TL * WP];
  const int tid = threadIdx.x;
  const int b   = blockIdx.y;
  const int m0  = blockIdx.x * TM;
  if (tid < TM * 16) qs[tid] = q[((size_t)b * Lc + m0) * 16 + tid];
  if (tid < TM) {
    Ms[tid] = Mrow[(size_t)b * Lc + m0 + tid];
    Ss[tid] = Sinv[(size_t)b * Lc + m0 + tid];
  }
  __syncthreads();
  float accr[TM] = {}, acci[TM] = {};
  const int lt = tid & 63;  // l within tile
  const int g  = tid >> 6;  // query group 0..3
  for (int l0 = 0; l0 < Lc; l0 += TL) {
    // Step A: weights for this l-tile (each thread: 1 key row x 4 queries)
    const float* kp = k + ((size_t)b * Lc + l0 + lt) * 16;
    float k0[16];
#pragma unroll
    for (int t = 0; t < 16; ++t) k0[t] = kp[t];
#pragma unroll
    for (int j = 0; j < 4; ++j) {
      const int mi = g * 4 + j;
      float er = 0.f, ei = 0.f;
#pragma unroll
      for (int d = 0; d < 8; ++d) {
        const float a = qs[mi * 16 + d], bb = qs[mi * 16 + 8 + d];
        const float cc = k0[d], dd = k0[8 + d];
        er += a * cc - bb * dd;
        ei += a * dd + bb * cc;
      }
      const float e = er * er + ei * ei;
      wls[lt * WP + mi] = expf(e - Ms[mi]) * Ss[mi];
    }
    __syncthreads();
    // Step B: PV accumulate — coalesced v loads, broadcast LDS weights
    const float* vrow = vT + ((size_t)b * Lc + l0) * (2 * CGc) + tid;
#pragma unroll 2
    for (int l = 0; l < TL; ++l) {
      const float vr = vrow[(size_t)l * (2 * CGc)];
      const float vi = vrow[(size_t)l * (2 * CGc) + CGc];
      const float* wp = &wls[l * WP];
#pragma unroll
      for (int mi = 0; mi < TM; ++mi) {
        accr[mi] += wp[mi] * vr;
        acci[mi] += wp[mi] * vi;
      }
    }
    __syncthreads();
  }
  const float gm = gamma[0];
#pragma unroll
  for (int mi = 0; mi < TM; ++mi) {
    const size_t i0 = ((size_t)(0 * Bc + b) * CGc + tid) * Lc + m0 + mi;
    const size_t i1 = ((size_t)(1 * Bc + b) * CGc + tid) * Lc + m0 + mi;
    out[i0] = gm * accr[mi] + x[i0];
    out[i1] = gm * acci[mi] + x[i1];
  }
}

// ---------------------------------------------------------------------------
extern "C" void kernel_launch(void* const* d_in, const int* in_sizes, int n_in,
                              void* d_out, int out_size, void* d_ws, size_t ws_size,
                              hipStream_t stream) {
  const float* x     = (const float*)d_in[0];
  const float* wq    = (const float*)d_in[1];
  const float* wk    = (const float*)d_in[2];
  const float* wv    = (const float*)d_in[3];
  const float* gamma = (const float*)d_in[4];
  float* out = (float*)d_out;

  // Workspace layout (floats): q | k | vT | M | Sinv | wvT  (~18.4 MB total)
  float* q    = (float*)d_ws;
  float* kk   = q    + (size_t)Bc * Lc * 16;
  float* vT   = kk   + (size_t)Bc * Lc * 16;
  float* Mrow = vT   + (size_t)Bc * Lc * 2 * CGc;
  float* Sinv = Mrow + (size_t)Bc * Lc;
  float* wvT  = Sinv + (size_t)Bc * Lc;

  wv_transpose<<<dim3((2 * CGc * CGc) / 256), 256, 0, stream>>>(wv, wvT);
  qk_proj<<<dim3(Lc / 256, Bc, 2), 256, 0, stream>>>(x, wq, wk, q, kk);
  v_proj<<<dim3(Lc / 16, Bc), 256, 0, stream>>>(x, wvT, vT);
  softmax_stats<<<dim3(Lc / 8, Bc), 256, 0, stream>>>(q, kk, Mrow, Sinv);
  attn_out<<<dim3(Lc / 16, Bc), 256, 0, stream>>>(q, kk, vT, Mrow, Sinv, x, gamma, out);
}

// Round 2
// 602.286 us; speedup vs baseline: 2.0357x; 2.0357x over previous
//
#include <hip/hip_runtime.h>
#include <cstdint>

// Shapes (fixed by the problem): B=2, C=64, G=4 -> CG=256, DQK=8, L=64*64=4096
constexpr int Bc  = 2;
constexpr int CGc = 256;
constexpr int Dc  = 8;
constexpr int Lc  = 4096;

typedef __attribute__((ext_vector_type(8))) short short8;
typedef __attribute__((ext_vector_type(4))) float floatx4;

__device__ inline unsigned short f2bf(float f) {
  union { float f; unsigned u; } v; v.f = f;
  unsigned r = v.u + 0x7fffu + ((v.u >> 16) & 1u);
  return (unsigned short)(r >> 16);
}

// ---------------------------------------------------------------------------
// Phase 0: transpose wv (2,CG,CG) [o][cin] -> wvT [cin][o].
// ---------------------------------------------------------------------------
__global__ __launch_bounds__(256) void wv_transpose(const float* __restrict__ wv,
                                                    float* __restrict__ wvT) {
  const int i    = blockIdx.x * 256 + threadIdx.x;
  const int comp = i >> 16;
  const int rem  = i & 65535;
  const int cin  = rem >> 8;
  const int c    = rem & 255;
  wvT[i] = wv[(size_t)(comp * CGc + c) * CGc + cin];
}

// ---------------------------------------------------------------------------
// Phase 1: complex Q/K projections (fp32 — softmax logits need full precision).
// ---------------------------------------------------------------------------
__global__ __launch_bounds__(256) void qk_proj(const float* __restrict__ x,
                                               const float* __restrict__ wq,
                                               const float* __restrict__ wk,
                                               float* __restrict__ qout,
                                               float* __restrict__ kout) {
  __shared__ float ws[2 * Dc * CGc];
  const int tid = threadIdx.x;
  const int b   = blockIdx.y;
  const int z   = blockIdx.z;
  const float* w = z ? wk : wq;
  float* o       = z ? kout : qout;
  for (int i = tid; i < 2 * Dc * CGc; i += 256) ws[i] = w[i];
  __syncthreads();
  const int m = blockIdx.x * 256 + tid;
  float ar_acc[Dc] = {}, ai_acc[Dc] = {};
  const float* xr = x + ((size_t)(0 * Bc + b) * CGc) * Lc + m;
  const float* xi = x + ((size_t)(1 * Bc + b) * CGc) * Lc + m;
  for (int c = 0; c < CGc; ++c) {
    const float vr = xr[(size_t)c * Lc];
    const float vi = xi[(size_t)c * Lc];
#pragma unroll
    for (int d = 0; d < Dc; ++d) {
      const float wr = ws[d * CGc + c];
      const float wi = ws[(Dc + d) * CGc + c];
      ar_acc[d] += wr * vr - wi * vi;
      ai_acc[d] += wr * vi + wi * vr;
    }
  }
  float* op = o + ((size_t)b * Lc + m) * 16;
#pragma unroll
  for (int d = 0; d < Dc; ++d) {
    op[d]     = ar_acc[d];
    op[8 + d] = ai_acc[d];
  }
}

// ---------------------------------------------------------------------------
// Phase 2: complex V projection, bf16, CC-MAJOR: v[b][cc][l] (cc=comp*256+c).
// k(=l)-contiguous rows -> MFMA A-operand ready for pv_gemm.
// ---------------------------------------------------------------------------
__global__ __launch_bounds__(256) void v_proj(const float* __restrict__ x,
                                              const float* __restrict__ wvT,
                                              unsigned short* __restrict__ vbf) {
  constexpr int TL = 16;
  __shared__ float xs[2 * CGc * TL];
  const int tid = threadIdx.x;
  const int b   = blockIdx.y;
  const int l0  = blockIdx.x * TL;
  for (int i = tid; i < 2 * CGc * TL; i += 256) {
    const int comp = i / (CGc * TL);
    const int rem  = i - comp * CGc * TL;
    const int cin  = rem >> 4;
    const int l    = rem & 15;
    xs[i] = x[((size_t)(comp * Bc + b) * CGc + cin) * Lc + l0 + l];
  }
  __syncthreads();
  float accr[TL] = {}, acci[TL] = {};
  const int c = tid;
  for (int cin = 0; cin < CGc; ++cin) {
    const float wr = wvT[(size_t)cin * CGc + c];
    const float wi = wvT[(size_t)(CGc + cin) * CGc + c];
    const float* xr = &xs[cin * TL];
    const float* xi = &xs[(CGc + cin) * TL];
#pragma unroll
    for (int l = 0; l < TL; ++l) {
      accr[l] += wr * xr[l] - wi * xi[l];
      acci[l] += wr * xi[l] + wi * xr[l];
    }
  }
#pragma unroll
  for (int l = 0; l < TL; ++l) {
    vbf[((size_t)b * 512 + c) * Lc + l0 + l]       = f2bf(accr[l]);
    vbf[((size_t)b * 512 + 256 + c) * Lc + l0 + l] = f2bf(acci[l]);
  }
}

// ---------------------------------------------------------------------------
// Phase 3: per-row softmax stats (max, 1/sum) over E[b,m,l] = |q(m).k(l)|^2.
// ---------------------------------------------------------------------------
__global__ __launch_bounds__(256) void softmax_stats(const float* __restrict__ q,
                                                     const float* __restrict__ k,
                                                     float* __restrict__ Mrow,
                                                     float* __restrict__ Sinv) {
  constexpr int TM = 8;
  __shared__ float qs[TM * 16];
  __shared__ float redm[256];
  __shared__ float reds[256];
  const int tid = threadIdx.x;
  const int b   = blockIdx.y;
  const int m0  = blockIdx.x * TM;
  if (tid < TM * 16) qs[tid] = q[((size_t)b * Lc + m0) * 16 + tid];
  __syncthreads();
  float mloc[TM], sloc[TM];
#pragma unroll
  for (int j = 0; j < TM; ++j) { mloc[j] = -1e30f; sloc[j] = 0.f; }
  for (int l = tid; l < Lc; l += 256) {
    const float* kp = k + ((size_t)b * Lc + l) * 16;
    float k0[16];
#pragma unroll
    for (int t = 0; t < 16; ++t) k0[t] = kp[t];
#pragma unroll
    for (int j = 0; j < TM; ++j) {
      float er = 0.f, ei = 0.f;
#pragma unroll
      for (int d = 0; d < 8; ++d) {
        const float a = qs[j * 16 + d], bb = qs[j * 16 + 8 + d];
        const float cc = k0[d], dd = k0[8 + d];
        er += a * cc - bb * dd;
        ei += a * dd + bb * cc;
      }
      const float e = er * er + ei * ei;
      if (e > mloc[j]) {
        sloc[j] = sloc[j] * expf(mloc[j] - e) + 1.f;
        mloc[j] = e;
      } else {
        sloc[j] += expf(e - mloc[j]);
      }
    }
  }
  for (int j = 0; j < TM; ++j) {
    redm[tid] = mloc[j];
    reds[tid] = sloc[j];
    __syncthreads();
    for (int off = 128; off > 0; off >>= 1) {
      if (tid < off) {
        const float m1 = redm[tid], m2 = redm[tid + off];
        const float s1 = reds[tid], s2 = reds[tid + off];
        const float mm = fmaxf(m1, m2);
        redm[tid] = mm;
        reds[tid] = s1 * expf(m1 - mm) + s2 * expf(m2 - mm);
      }
      __syncthreads();
    }
    if (tid == 0) {
      Mrow[(size_t)b * Lc + m0 + j] = redm[0];
      Sinv[(size_t)b * Lc + m0 + j] = 1.f / reds[0];
    }
    __syncthreads();
  }
}

// ---------------------------------------------------------------------------
// Phase 4: materialize att[b][m][l] in bf16 (m-major rows, l contiguous =
// MFMA B-operand ready). E recomputed in fp32; w = exp(e-M)*Sinv.
// grid (L/32, B); 32 queries per block; k tiles staged d-major in LDS.
// ---------------------------------------------------------------------------
__global__ __launch_bounds__(256) void att_write(const float* __restrict__ q,
                                                 const float* __restrict__ kg,
                                                 const float* __restrict__ Mrow,
                                                 const float* __restrict__ Sinv,
                                                 unsigned short* __restrict__ att) {
  __shared__ float qs[32 * 16];
  __shared__ float Ms[32], Ss[32];
  __shared__ float ks[16 * 66];  // d-major, pad 66 -> conflict-free reads
  const int tid = threadIdx.x;
  const int b   = blockIdx.y;
  const int m0  = blockIdx.x * 32;
  for (int i = tid; i < 32 * 16; i += 256) qs[i] = q[((size_t)b * Lc + m0) * 16 + i];
  if (tid < 32) {
    Ms[tid] = Mrow[(size_t)b * Lc + m0 + tid];
    Ss[tid] = Sinv[(size_t)b * Lc + m0 + tid];
  }
  __syncthreads();
  const int lt   = tid & 63;
  const int mg   = tid >> 6;
  const int srow = tid >> 2, scol = (tid & 3) * 4;
  for (int pass = 0; pass < 2; ++pass) {
    const int mb = mg * 8 + pass * 4;
    float qv[4][16];
#pragma unroll
    for (int j = 0; j < 4; ++j)
#pragma unroll
      for (int t = 0; t < 16; ++t) qv[j][t] = qs[(mb + j) * 16 + t];
    float Mv[4], Sv[4];
#pragma unroll
    for (int j = 0; j < 4; ++j) { Mv[j] = Ms[mb + j]; Sv[j] = Ss[mb + j]; }
    for (int l0 = 0; l0 < Lc; l0 += 64) {
      __syncthreads();
      const float4 kv = *(const float4*)(kg + ((size_t)b * Lc + l0 + srow) * 16 + scol);
      ks[(scol + 0) * 66 + srow] = kv.x;
      ks[(scol + 1) * 66 + srow] = kv.y;
      ks[(scol + 2) * 66 + srow] = kv.z;
      ks[(scol + 3) * 66 + srow] = kv.w;
      __syncthreads();
      float k0[16];
#pragma unroll
      for (int t = 0; t < 16; ++t) k0[t] = ks[t * 66 + lt];
#pragma unroll
      for (int j = 0; j < 4; ++j) {
        float er = 0.f, ei = 0.f;
#pragma unroll
        for (int d = 0; d < 8; ++d) {
          er += qv[j][d] * k0[d] - qv[j][8 + d] * k0[8 + d];
          ei += qv[j][d] * k0[8 + d] + qv[j][8 + d] * k0[d];
        }
        const float e = er * er + ei * ei;
        const float w = expf(e - Mv[j]) * Sv[j];
        att[((size_t)b * Lc + m0 + mb + j) * Lc + l0 + lt] = f2bf(w);
      }
    }
  }
}

// ---------------------------------------------------------------------------
// Phase 5: PV GEMM via bf16 MFMA.  C[cc][m] = sum_l v[cc][l] * att[m][l].
// Both operands are k(=l)-contiguous -> row-major LDS tiles, ds_read_b128
// frag loads.  Block tile 128cc x 128m x BK64; 4 waves of 64x64 (4x4 frags).
// Epilogue: out = gamma*acc + x, coalesced over m (C col = lane&15).
// ---------------------------------------------------------------------------
__global__ __launch_bounds__(256) void pv_gemm(const unsigned short* __restrict__ v,
                                               const unsigned short* __restrict__ att,
                                               const float* __restrict__ x,
                                               const float* __restrict__ gamma,
                                               float* __restrict__ out) {
  constexpr int LDK = 72;  // 64 + 8 pad: 144B rows -> bank phase 4, <=2-way
  __shared__ short As[128 * LDK];  // v tile   [cc][k]
  __shared__ short Bs[128 * LDK];  // att tile [m][k]
  const int tid  = threadIdx.x;
  const int b    = blockIdx.z;
  const int cc0  = blockIdx.y * 128;
  const int m0   = blockIdx.x * 128;
  const int wid  = tid >> 6, lane = tid & 63;
  const int wcc  = (wid >> 1) * 64;
  const int wm   = (wid & 1) * 64;
  const int lrow = lane & 15, quad = lane >> 4;
  floatx4 acc[4][4] = {};
  const unsigned short* vsrc = v   + ((size_t)b * 512 + cc0) * Lc;
  const unsigned short* asrc = att + ((size_t)b * Lc + m0) * Lc;
  for (int k0 = 0; k0 < Lc; k0 += 64) {
    short8 ar[4], br[4];
#pragma unroll
    for (int rnd = 0; rnd < 4; ++rnd) {
      const int idx = rnd * 256 + tid;
      const int row = idx >> 3, ch = idx & 7;
      ar[rnd] = *(const short8*)(vsrc + (size_t)row * Lc + k0 + ch * 8);
      br[rnd] = *(const short8*)(asrc + (size_t)row * Lc + k0 + ch * 8);
    }
    __syncthreads();
#pragma unroll
    for (int rnd = 0; rnd < 4; ++rnd) {
      const int idx = rnd * 256 + tid;
      const int row = idx >> 3, ch = idx & 7;
      *(short8*)&As[row * LDK + ch * 8] = ar[rnd];
      *(short8*)&Bs[row * LDK + ch * 8] = br[rnd];
    }
    __syncthreads();
#pragma unroll
    for (int kk = 0; kk < 64; kk += 32) {
      short8 af[4], bf[4];
#pragma unroll
      for (int i = 0; i < 4; ++i)
        af[i] = *(const short8*)&As[(wcc + i * 16 + lrow) * LDK + kk + quad * 8];
#pragma unroll
      for (int j = 0; j < 4; ++j)
        bf[j] = *(const short8*)&Bs[(wm + j * 16 + lrow) * LDK + kk + quad * 8];
#pragma unroll
      for (int i = 0; i < 4; ++i)
#pragma unroll
        for (int j = 0; j < 4; ++j)
          acc[i][j] = __builtin_amdgcn_mfma_f32_16x16x32_bf16(af[i], bf[j], acc[i][j], 0, 0, 0);
    }
  }
  const float gm = gamma[0];
#pragma unroll
  for (int i = 0; i < 4; ++i) {
    const int ccb = cc0 + wcc + i * 16 + quad * 4;
#pragma unroll
    for (int j = 0; j < 4; ++j) {
      const int m = m0 + wm + j * 16 + lrow;
#pragma unroll
      for (int rg = 0; rg < 4; ++rg) {
        const int cc   = ccb + rg;
        const int comp = cc >> 8, c = cc & 255;
        const size_t idx = (((size_t)comp * Bc + b) * CGc + c) * Lc + m;
        out[idx] = gm * acc[i][j][rg] + x[idx];
      }
    }
  }
}

// ---------------------------------------------------------------------------
extern "C" void kernel_launch(void* const* d_in, const int* in_sizes, int n_in,
                              void* d_out, int out_size, void* d_ws, size_t ws_size,
                              hipStream_t stream) {
  const float* x     = (const float*)d_in[0];
  const float* wq    = (const float*)d_in[1];
  const float* wk    = (const float*)d_in[2];
  const float* wv    = (const float*)d_in[3];
  const float* gamma = (const float*)d_in[4];
  float* out = (float*)d_out;

  // Workspace (fp32 then bf16 blocks; ~74 MB total):
  float* q    = (float*)d_ws;                    // 2*4096*16
  float* kk   = q    + (size_t)Bc * Lc * 16;     // 2*4096*16
  float* wvT  = kk   + (size_t)Bc * Lc * 16;     // 2*256*256
  float* Mrow = wvT  + (size_t)2 * CGc * CGc;    // 2*4096
  float* Sinv = Mrow + (size_t)Bc * Lc;          // 2*4096
  unsigned short* vbf = (unsigned short*)(Sinv + (size_t)Bc * Lc);  // 2*512*4096
  unsigned short* att = vbf + (size_t)Bc * 512 * Lc;                // 2*4096*4096

  wv_transpose<<<dim3((2 * CGc * CGc) / 256), 256, 0, stream>>>(wv, wvT);
  qk_proj<<<dim3(Lc / 256, Bc, 2), 256, 0, stream>>>(x, wq, wk, q, kk);
  v_proj<<<dim3(Lc / 16, Bc), 256, 0, stream>>>(x, wvT, vbf);
  softmax_stats<<<dim3(Lc / 8, Bc), 256, 0, stream>>>(q, kk, Mrow, Sinv);
  att_write<<<dim3(Lc / 32, Bc), 256, 0, stream>>>(q, kk, Mrow, Sinv, att);
  pv_gemm<<<dim3(Lc / 128, 512 / 128, Bc), 256, 0, stream>>>(vbf, att, x, gamma, out);
}

// Round 3
// 489.780 us; speedup vs baseline: 2.5034x; 1.2297x over previous
//
#include <hip/hip_runtime.h>
#include <cstdint>

// Shapes (fixed by the problem): B=2, C=64, G=4 -> CG=256, DQK=8, L=64*64=4096
constexpr int Bc  = 2;
constexpr int CGc = 256;
constexpr int Dc  = 8;
constexpr int Lc  = 4096;

typedef __attribute__((ext_vector_type(8))) short short8;
typedef __attribute__((ext_vector_type(4))) float floatx4;

__device__ inline unsigned short f2bf(float f) {
  union { float f; unsigned u; } v; v.f = f;
  unsigned r = v.u + 0x7fffu + ((v.u >> 16) & 1u);
  return (unsigned short)(r >> 16);
}

// ---------------------------------------------------------------------------
// Phase 0: transpose wv (2,CG,CG) [o][cin] -> wvT [cin][o].
// ---------------------------------------------------------------------------
__global__ __launch_bounds__(256) void wv_transpose(const float* __restrict__ wv,
                                                    float* __restrict__ wvT) {
  const int i    = blockIdx.x * 256 + threadIdx.x;
  const int comp = i >> 16;
  const int rem  = i & 65535;
  const int cin  = rem >> 8;
  const int c    = rem & 255;
  wvT[i] = wv[(size_t)(comp * CGc + c) * CGc + cin];
}

// ---------------------------------------------------------------------------
// Phase 1: complex Q/K projections (fp32 — softmax logits need full precision).
// ---------------------------------------------------------------------------
__global__ __launch_bounds__(256) void qk_proj(const float* __restrict__ x,
                                               const float* __restrict__ wq,
                                               const float* __restrict__ wk,
                                               float* __restrict__ qout,
                                               float* __restrict__ kout) {
  __shared__ float ws[2 * Dc * CGc];
  const int tid = threadIdx.x;
  const int b   = blockIdx.y;
  const int z   = blockIdx.z;
  const float* w = z ? wk : wq;
  float* o       = z ? kout : qout;
  for (int i = tid; i < 2 * Dc * CGc; i += 256) ws[i] = w[i];
  __syncthreads();
  const int m = blockIdx.x * 256 + tid;
  float ar_acc[Dc] = {}, ai_acc[Dc] = {};
  const float* xr = x + ((size_t)(0 * Bc + b) * CGc) * Lc + m;
  const float* xi = x + ((size_t)(1 * Bc + b) * CGc) * Lc + m;
  for (int c = 0; c < CGc; ++c) {
    const float vr = xr[(size_t)c * Lc];
    const float vi = xi[(size_t)c * Lc];
#pragma unroll
    for (int d = 0; d < Dc; ++d) {
      const float wr = ws[d * CGc + c];
      const float wi = ws[(Dc + d) * CGc + c];
      ar_acc[d] += wr * vr - wi * vi;
      ai_acc[d] += wr * vi + wi * vr;
    }
  }
  float* op = o + ((size_t)b * Lc + m) * 16;
#pragma unroll
  for (int d = 0; d < Dc; ++d) {
    op[d]     = ar_acc[d];
    op[8 + d] = ai_acc[d];
  }
}

// ---------------------------------------------------------------------------
// Phase 2: complex V projection, bf16, CC-MAJOR: v[b][cc][l] (cc=comp*256+c).
// k(=l)-contiguous rows -> MFMA A-operand ready for pv_gemm.
// ---------------------------------------------------------------------------
__global__ __launch_bounds__(256) void v_proj(const float* __restrict__ x,
                                              const float* __restrict__ wvT,
                                              unsigned short* __restrict__ vbf) {
  constexpr int TL = 16;
  __shared__ float xs[2 * CGc * TL];
  const int tid = threadIdx.x;
  const int b   = blockIdx.y;
  const int l0  = blockIdx.x * TL;
  for (int i = tid; i < 2 * CGc * TL; i += 256) {
    const int comp = i / (CGc * TL);
    const int rem  = i - comp * CGc * TL;
    const int cin  = rem >> 4;
    const int l    = rem & 15;
    xs[i] = x[((size_t)(comp * Bc + b) * CGc + cin) * Lc + l0 + l];
  }
  __syncthreads();
  float accr[TL] = {}, acci[TL] = {};
  const int c = tid;
  for (int cin = 0; cin < CGc; ++cin) {
    const float wr = wvT[(size_t)cin * CGc + c];
    const float wi = wvT[(size_t)(CGc + cin) * CGc + c];
    const float* xr = &xs[cin * TL];
    const float* xi = &xs[(CGc + cin) * TL];
#pragma unroll
    for (int l = 0; l < TL; ++l) {
      accr[l] += wr * xr[l] - wi * xi[l];
      acci[l] += wr * xi[l] + wi * xr[l];
    }
  }
#pragma unroll
  for (int l = 0; l < TL; ++l) {
    vbf[((size_t)b * 512 + c) * Lc + l0 + l]       = f2bf(accr[l]);
    vbf[((size_t)b * 512 + 256 + c) * Lc + l0 + l] = f2bf(acci[l]);
  }
}

// ---------------------------------------------------------------------------
// Phase 3: row max of E[b,m,l] = |q(m).k(l)|^2.  Branchless, NO exp.
// grid (L/16, B); 4 waves/block, 4 rows/wave; k-tile (64 rows) staged d-major
// in LDS (pad 66 -> conflict-free broadcast-ish reads); wave-butterfly max.
// ---------------------------------------------------------------------------
__global__ __launch_bounds__(256) void softmax_max(const float* __restrict__ q,
                                                   const float* __restrict__ kg,
                                                   float* __restrict__ Mrow) {
  __shared__ float ks[16 * 66];
  const int tid  = threadIdx.x;
  const int b    = blockIdx.y;
  const int m0   = blockIdx.x * 16;
  const int w    = tid >> 6, lt = tid & 63;
  const int srow = tid >> 2, scol = (tid & 3) * 4;
  const int mb   = m0 + w * 4;
  float qv[4][16];
#pragma unroll
  for (int j = 0; j < 4; ++j)
#pragma unroll
    for (int t = 0; t < 16; ++t) qv[j][t] = q[((size_t)b * Lc + mb + j) * 16 + t];
  float mx[4] = {-1e30f, -1e30f, -1e30f, -1e30f};
  for (int l0 = 0; l0 < Lc; l0 += 64) {
    __syncthreads();
    const float4 kv = *(const float4*)(kg + ((size_t)b * Lc + l0 + srow) * 16 + scol);
    ks[(scol + 0) * 66 + srow] = kv.x;
    ks[(scol + 1) * 66 + srow] = kv.y;
    ks[(scol + 2) * 66 + srow] = kv.z;
    ks[(scol + 3) * 66 + srow] = kv.w;
    __syncthreads();
    float k0[16];
#pragma unroll
    for (int t = 0; t < 16; ++t) k0[t] = ks[t * 66 + lt];
#pragma unroll
    for (int j = 0; j < 4; ++j) {
      float er = 0.f, ei = 0.f;
#pragma unroll
      for (int d = 0; d < 8; ++d) {
        er += qv[j][d] * k0[d] - qv[j][8 + d] * k0[8 + d];
        ei += qv[j][d] * k0[8 + d] + qv[j][8 + d] * k0[d];
      }
      mx[j] = fmaxf(mx[j], er * er + ei * ei);
    }
  }
#pragma unroll
  for (int j = 0; j < 4; ++j) {
#pragma unroll
    for (int off = 32; off > 0; off >>= 1) mx[j] = fmaxf(mx[j], __shfl_xor(mx[j], off));
    if (lt == 0) Mrow[(size_t)b * Lc + mb + j] = mx[j];
  }
}

// ---------------------------------------------------------------------------
// Phase 4: att[b][m][l] = bf16(__expf(E - M)) (UNNORMALIZED, in [0,1]) and
// row sums -> Sinv = 1/S (normalization folded into pv_gemm epilogue).
// Same structure as softmax_max; one extra v_exp + store per element.
// ---------------------------------------------------------------------------
__global__ __launch_bounds__(256) void att_exp(const float* __restrict__ q,
                                               const float* __restrict__ kg,
                                               const float* __restrict__ Mrow,
                                               unsigned short* __restrict__ att,
                                               float* __restrict__ Sinv) {
  __shared__ float ks[16 * 66];
  const int tid  = threadIdx.x;
  const int b    = blockIdx.y;
  const int m0   = blockIdx.x * 16;
  const int w    = tid >> 6, lt = tid & 63;
  const int srow = tid >> 2, scol = (tid & 3) * 4;
  const int mb   = m0 + w * 4;
  float qv[4][16];
  float Mv[4], sum[4] = {};
#pragma unroll
  for (int j = 0; j < 4; ++j) {
#pragma unroll
    for (int t = 0; t < 16; ++t) qv[j][t] = q[((size_t)b * Lc + mb + j) * 16 + t];
    Mv[j] = Mrow[(size_t)b * Lc + mb + j];
  }
  for (int l0 = 0; l0 < Lc; l0 += 64) {
    __syncthreads();
    const float4 kv = *(const float4*)(kg + ((size_t)b * Lc + l0 + srow) * 16 + scol);
    ks[(scol + 0) * 66 + srow] = kv.x;
    ks[(scol + 1) * 66 + srow] = kv.y;
    ks[(scol + 2) * 66 + srow] = kv.z;
    ks[(scol + 3) * 66 + srow] = kv.w;
    __syncthreads();
    float k0[16];
#pragma unroll
    for (int t = 0; t < 16; ++t) k0[t] = ks[t * 66 + lt];
#pragma unroll
    for (int j = 0; j < 4; ++j) {
      float er = 0.f, ei = 0.f;
#pragma unroll
      for (int d = 0; d < 8; ++d) {
        er += qv[j][d] * k0[d] - qv[j][8 + d] * k0[8 + d];
        ei += qv[j][d] * k0[8 + d] + qv[j][8 + d] * k0[d];
      }
      const float wgt = __expf(er * er + ei * ei - Mv[j]);
      sum[j] += wgt;
      att[((size_t)b * Lc + mb + j) * Lc + l0 + lt] = f2bf(wgt);
    }
  }
#pragma unroll
  for (int j = 0; j < 4; ++j) {
#pragma unroll
    for (int off = 32; off > 0; off >>= 1) sum[j] += __shfl_xor(sum[j], off);
    if (lt == 0) Sinv[(size_t)b * Lc + mb + j] = 1.f / sum[j];
  }
}

// ---------------------------------------------------------------------------
// Phase 5: PV GEMM via bf16 MFMA.  C[cc][m] = sum_l v[cc][l] * att[m][l].
// Epilogue applies per-column Sinv[m] (softmax normalization) and gamma,
// then out = . + x.  Block tile 128cc x 128m x BK64; 4 waves of 64x64.
// ---------------------------------------------------------------------------
__global__ __launch_bounds__(256) void pv_gemm(const unsigned short* __restrict__ v,
                                               const unsigned short* __restrict__ att,
                                               const float* __restrict__ Sinv,
                                               const float* __restrict__ x,
                                               const float* __restrict__ gamma,
                                               float* __restrict__ out) {
  constexpr int LDK = 72;  // 64 + 8 pad: <=2-way bank aliasing on frag reads
  __shared__ short As[128 * LDK];  // v tile   [cc][k]
  __shared__ short Bs[128 * LDK];  // att tile [m][k]
  const int tid  = threadIdx.x;
  const int b    = blockIdx.z;
  const int cc0  = blockIdx.y * 128;
  const int m0   = blockIdx.x * 128;
  const int wid  = tid >> 6, lane = tid & 63;
  const int wcc  = (wid >> 1) * 64;
  const int wm   = (wid & 1) * 64;
  const int lrow = lane & 15, quad = lane >> 4;
  floatx4 acc[4][4] = {};
  const unsigned short* vsrc = v   + ((size_t)b * 512 + cc0) * Lc;
  const unsigned short* asrc = att + ((size_t)b * Lc + m0) * Lc;
  for (int k0 = 0; k0 < Lc; k0 += 64) {
    short8 ar[4], br[4];
#pragma unroll
    for (int rnd = 0; rnd < 4; ++rnd) {
      const int idx = rnd * 256 + tid;
      const int row = idx >> 3, ch = idx & 7;
      ar[rnd] = *(const short8*)(vsrc + (size_t)row * Lc + k0 + ch * 8);
      br[rnd] = *(const short8*)(asrc + (size_t)row * Lc + k0 + ch * 8);
    }
    __syncthreads();
#pragma unroll
    for (int rnd = 0; rnd < 4; ++rnd) {
      const int idx = rnd * 256 + tid;
      const int row = idx >> 3, ch = idx & 7;
      *(short8*)&As[row * LDK + ch * 8] = ar[rnd];
      *(short8*)&Bs[row * LDK + ch * 8] = br[rnd];
    }
    __syncthreads();
#pragma unroll
    for (int kk = 0; kk < 64; kk += 32) {
      short8 af[4], bf[4];
#pragma unroll
      for (int i = 0; i < 4; ++i)
        af[i] = *(const short8*)&As[(wcc + i * 16 + lrow) * LDK + kk + quad * 8];
#pragma unroll
      for (int j = 0; j < 4; ++j)
        bf[j] = *(const short8*)&Bs[(wm + j * 16 + lrow) * LDK + kk + quad * 8];
#pragma unroll
      for (int i = 0; i < 4; ++i)
#pragma unroll
        for (int j = 0; j < 4; ++j)
          acc[i][j] = __builtin_amdgcn_mfma_f32_16x16x32_bf16(af[i], bf[j], acc[i][j], 0, 0, 0);
    }
  }
  const float gm = gamma[0];
  float svj[4];
#pragma unroll
  for (int j = 0; j < 4; ++j)
    svj[j] = gm * Sinv[(size_t)b * Lc + m0 + wm + j * 16 + lrow];
#pragma unroll
  for (int i = 0; i < 4; ++i) {
    const int ccb = cc0 + wcc + i * 16 + quad * 4;
#pragma unroll
    for (int j = 0; j < 4; ++j) {
      const int m = m0 + wm + j * 16 + lrow;
#pragma unroll
      for (int rg = 0; rg < 4; ++rg) {
        const int cc   = ccb + rg;
        const int comp = cc >> 8, c = cc & 255;
        const size_t idx = (((size_t)comp * Bc + b) * CGc + c) * Lc + m;
        out[idx] = svj[j] * acc[i][j][rg] + x[idx];
      }
    }
  }
}

// ---------------------------------------------------------------------------
extern "C" void kernel_launch(void* const* d_in, const int* in_sizes, int n_in,
                              void* d_out, int out_size, void* d_ws, size_t ws_size,
                              hipStream_t stream) {
  const float* x     = (const float*)d_in[0];
  const float* wq    = (const float*)d_in[1];
  const float* wk    = (const float*)d_in[2];
  const float* wv    = (const float*)d_in[3];
  const float* gamma = (const float*)d_in[4];
  float* out = (float*)d_out;

  // Workspace (fp32 then bf16 blocks; ~74 MB total):
  float* q    = (float*)d_ws;                    // 2*4096*16
  float* kk   = q    + (size_t)Bc * Lc * 16;     // 2*4096*16
  float* wvT  = kk   + (size_t)Bc * Lc * 16;     // 2*256*256
  float* Mrow = wvT  + (size_t)2 * CGc * CGc;    // 2*4096
  float* Sinv = Mrow + (size_t)Bc * Lc;          // 2*4096
  unsigned short* vbf = (unsigned short*)(Sinv + (size_t)Bc * Lc);  // 2*512*4096
  unsigned short* att = vbf + (size_t)Bc * 512 * Lc;                // 2*4096*4096

  wv_transpose<<<dim3((2 * CGc * CGc) / 256), 256, 0, stream>>>(wv, wvT);
  qk_proj<<<dim3(Lc / 256, Bc, 2), 256, 0, stream>>>(x, wq, wk, q, kk);
  v_proj<<<dim3(Lc / 16, Bc), 256, 0, stream>>>(x, wvT, vbf);
  softmax_max<<<dim3(Lc / 16, Bc), 256, 0, stream>>>(q, kk, Mrow);
  att_exp<<<dim3(Lc / 16, Bc), 256, 0, stream>>>(q, kk, Mrow, att, Sinv);
  pv_gemm<<<dim3(Lc / 128, 512 / 128, Bc), 256, 0, stream>>>(vbf, att, Sinv, x, gamma, out);
}

// Round 4
// 398.686 us; speedup vs baseline: 3.0754x; 1.2285x over previous
//
#include <hip/hip_runtime.h>
#include <cstdint>

// Shapes (fixed by the problem): B=2, C=64, G=4 -> CG=256, DQK=8, L=64*64=4096
constexpr int Bc  = 2;
constexpr int CGc = 256;
constexpr int Dc  = 8;
constexpr int Lc  = 4096;

typedef __attribute__((ext_vector_type(8))) short short8;
typedef __attribute__((ext_vector_type(4))) float floatx4;

__device__ inline unsigned short f2bf(float f) {
  union { float f; unsigned u; } v; v.f = f;
  unsigned r = v.u + 0x7fffu + ((v.u >> 16) & 1u);
  return (unsigned short)(r >> 16);
}

// ---------------------------------------------------------------------------
// Phase 0: transpose wv (2,CG,CG) [o][cin] -> wvT [comp][cin][o].
// ---------------------------------------------------------------------------
__global__ __launch_bounds__(256) void wv_transpose(const float* __restrict__ wv,
                                                    float* __restrict__ wvT) {
  const int i    = blockIdx.x * 256 + threadIdx.x;
  const int comp = i >> 16;
  const int rem  = i & 65535;
  const int cin  = rem >> 8;
  const int c    = rem & 255;
  wvT[i] = wv[(size_t)(comp * CGc + c) * CGc + cin];
}

// ---------------------------------------------------------------------------
// Phase 1: complex Q/K projections (fp32 — softmax logits need full precision).
// ---------------------------------------------------------------------------
__global__ __launch_bounds__(256) void qk_proj(const float* __restrict__ x,
                                               const float* __restrict__ wq,
                                               const float* __restrict__ wk,
                                               float* __restrict__ qout,
                                               float* __restrict__ kout) {
  __shared__ float ws[2 * Dc * CGc];
  const int tid = threadIdx.x;
  const int b   = blockIdx.y;
  const int z   = blockIdx.z;
  const float* w = z ? wk : wq;
  float* o       = z ? kout : qout;
  for (int i = tid; i < 2 * Dc * CGc; i += 256) ws[i] = w[i];
  __syncthreads();
  const int m = blockIdx.x * 256 + tid;
  float ar_acc[Dc] = {}, ai_acc[Dc] = {};
  const float* xr = x + ((size_t)(0 * Bc + b) * CGc) * Lc + m;
  const float* xi = x + ((size_t)(1 * Bc + b) * CGc) * Lc + m;
  for (int c = 0; c < CGc; ++c) {
    const float vr = xr[(size_t)c * Lc];
    const float vi = xi[(size_t)c * Lc];
#pragma unroll
    for (int d = 0; d < Dc; ++d) {
      const float wr = ws[d * CGc + c];
      const float wi = ws[(Dc + d) * CGc + c];
      ar_acc[d] += wr * vr - wi * vi;
      ai_acc[d] += wr * vi + wi * vr;
    }
  }
  float* op = o + ((size_t)b * Lc + m) * 16;
#pragma unroll
  for (int d = 0; d < Dc; ++d) {
    op[d]     = ar_acc[d];
    op[8 + d] = ai_acc[d];
  }
}

// ---------------------------------------------------------------------------
// Phase 2: complex V projection, bf16, CC-MAJOR: v[b][cc][l]. No LDS, no
// barriers: lanes = l (coalesced x loads + stores), w wave-uniform (s_load).
// Wave covers 64 l x 16 c; block = 4 waves = 64 c; grid (L/64, CG/64, B).
// ---------------------------------------------------------------------------
__global__ __launch_bounds__(256) void v_proj(const float* __restrict__ x,
                                              const float* __restrict__ wvT,
                                              unsigned short* __restrict__ vbf) {
  const int tid = threadIdx.x;
  const int wv  = __builtin_amdgcn_readfirstlane(tid >> 6);
  const int lt  = tid & 63;
  const int b   = blockIdx.z;
  const int c0  = blockIdx.y * 64 + wv * 16;
  const int l   = blockIdx.x * 64 + lt;
  const float* xr = x + ((size_t)(0 * Bc + b) * CGc) * Lc + l;
  const float* xi = x + ((size_t)(1 * Bc + b) * CGc) * Lc + l;
  float vr[16] = {}, vi[16] = {};
#pragma unroll 2
  for (int cin = 0; cin < CGc; ++cin) {
    const float xrv = xr[(size_t)cin * Lc];
    const float xiv = xi[(size_t)cin * Lc];
    const float* wrp = wvT + (size_t)cin * CGc + c0;            // comp 0
    const float* wip = wvT + (size_t)(CGc + cin) * CGc + c0;    // comp 1
#pragma unroll
    for (int ci = 0; ci < 16; ++ci) {
      const float wr = wrp[ci], wi = wip[ci];
      vr[ci] = fmaf(wr, xrv, vr[ci]);
      vr[ci] = fmaf(-wi, xiv, vr[ci]);
      vi[ci] = fmaf(wr, xiv, vi[ci]);
      vi[ci] = fmaf(wi, xrv, vi[ci]);
    }
  }
#pragma unroll
  for (int ci = 0; ci < 16; ++ci) {
    vbf[((size_t)b * 512 + (c0 + ci)) * Lc + l]       = f2bf(vr[ci]);
    vbf[((size_t)b * 512 + 256 + (c0 + ci)) * Lc + l] = f2bf(vi[ci]);
  }
}

// ---------------------------------------------------------------------------
// Phase 3: row max of E[b,m,l] = |q(m).k(l)|^2.  No LDS/barriers: each wave
// owns 4 rows (q wave-uniform -> scalar regs), lane lt streams k[l0+lt][:]
// directly from global (K panel = 256 KB/b, L2-resident). Butterfly max.
// ---------------------------------------------------------------------------
__global__ __launch_bounds__(256) void softmax_max(const float* __restrict__ q,
                                                   const float* __restrict__ kg,
                                                   float* __restrict__ Mrow) {
  const int tid = threadIdx.x;
  const int wv  = __builtin_amdgcn_readfirstlane(tid >> 6);
  const int lt  = tid & 63;
  const int b   = blockIdx.y;
  const int mb  = blockIdx.x * 16 + wv * 4;
  float qv[4][16];
#pragma unroll
  for (int j = 0; j < 4; ++j)
#pragma unroll
    for (int t = 0; t < 16; ++t) qv[j][t] = q[((size_t)b * Lc + mb + j) * 16 + t];
  float mx[4] = {-1e30f, -1e30f, -1e30f, -1e30f};
  const float* kbase = kg + ((size_t)b * Lc + lt) * 16;
#pragma unroll 2
  for (int l0 = 0; l0 < Lc; l0 += 64) {
    const float4 ka = *(const float4*)(kbase + (size_t)l0 * 16 + 0);
    const float4 kb = *(const float4*)(kbase + (size_t)l0 * 16 + 4);
    const float4 kc = *(const float4*)(kbase + (size_t)l0 * 16 + 8);
    const float4 kd = *(const float4*)(kbase + (size_t)l0 * 16 + 12);
    const float k0[16] = {ka.x, ka.y, ka.z, ka.w, kb.x, kb.y, kb.z, kb.w,
                          kc.x, kc.y, kc.z, kc.w, kd.x, kd.y, kd.z, kd.w};
#pragma unroll
    for (int j = 0; j < 4; ++j) {
      float er = 0.f, ei = 0.f;
#pragma unroll
      for (int d = 0; d < 8; ++d) {
        er += qv[j][d] * k0[d] - qv[j][8 + d] * k0[8 + d];
        ei += qv[j][d] * k0[8 + d] + qv[j][8 + d] * k0[d];
      }
      mx[j] = fmaxf(mx[j], er * er + ei * ei);
    }
  }
#pragma unroll
  for (int j = 0; j < 4; ++j) {
#pragma unroll
    for (int off = 32; off > 0; off >>= 1) mx[j] = fmaxf(mx[j], __shfl_xor(mx[j], off));
    if (lt == 0) Mrow[(size_t)b * Lc + mb + j] = mx[j];
  }
}

// ---------------------------------------------------------------------------
// Phase 4: att[m][l] = bf16(__expf(E-M)) (unnormalized) + row sums -> Sinv.
// Same barrier-free structure as softmax_max; coalesced bf16 row stores.
// ---------------------------------------------------------------------------
__global__ __launch_bounds__(256) void att_exp(const float* __restrict__ q,
                                               const float* __restrict__ kg,
                                               const float* __restrict__ Mrow,
                                               unsigned short* __restrict__ att,
                                               float* __restrict__ Sinv) {
  const int tid = threadIdx.x;
  const int wv  = __builtin_amdgcn_readfirstlane(tid >> 6);
  const int lt  = tid & 63;
  const int b   = blockIdx.y;
  const int mb  = blockIdx.x * 16 + wv * 4;
  float qv[4][16], Mv[4], sum[4] = {};
#pragma unroll
  for (int j = 0; j < 4; ++j) {
#pragma unroll
    for (int t = 0; t < 16; ++t) qv[j][t] = q[((size_t)b * Lc + mb + j) * 16 + t];
    Mv[j] = Mrow[(size_t)b * Lc + mb + j];
  }
  const float* kbase = kg + ((size_t)b * Lc + lt) * 16;
  unsigned short* arow = att + ((size_t)b * Lc + mb) * Lc + lt;
#pragma unroll 2
  for (int l0 = 0; l0 < Lc; l0 += 64) {
    const float4 ka = *(const float4*)(kbase + (size_t)l0 * 16 + 0);
    const float4 kb = *(const float4*)(kbase + (size_t)l0 * 16 + 4);
    const float4 kc = *(const float4*)(kbase + (size_t)l0 * 16 + 8);
    const float4 kd = *(const float4*)(kbase + (size_t)l0 * 16 + 12);
    const float k0[16] = {ka.x, ka.y, ka.z, ka.w, kb.x, kb.y, kb.z, kb.w,
                          kc.x, kc.y, kc.z, kc.w, kd.x, kd.y, kd.z, kd.w};
#pragma unroll
    for (int j = 0; j < 4; ++j) {
      float er = 0.f, ei = 0.f;
#pragma unroll
      for (int d = 0; d < 8; ++d) {
        er += qv[j][d] * k0[d] - qv[j][8 + d] * k0[8 + d];
        ei += qv[j][d] * k0[8 + d] + qv[j][8 + d] * k0[d];
      }
      const float wgt = __expf(er * er + ei * ei - Mv[j]);
      sum[j] += wgt;
      arow[(size_t)j * Lc + l0] = f2bf(wgt);
    }
  }
#pragma unroll
  for (int j = 0; j < 4; ++j) {
#pragma unroll
    for (int off = 32; off > 0; off >>= 1) sum[j] += __shfl_xor(sum[j], off);
    if (lt == 0) Sinv[(size_t)b * Lc + mb + j] = 1.f / sum[j];
  }
}

// ---------------------------------------------------------------------------
// Phase 5: PV GEMM via bf16 MFMA.  C[cc][m] = sum_l v[cc][l] * att[m][l].
// Grid ordered cc-fastest so consecutive blocks share the att m-panel (L2
// reuse: att read ~once from HBM).  Epilogue: out = gamma*Sinv[m]*acc + x.
// ---------------------------------------------------------------------------
__global__ __launch_bounds__(256) void pv_gemm(const unsigned short* __restrict__ v,
                                               const unsigned short* __restrict__ att,
                                               const float* __restrict__ Sinv,
                                               const float* __restrict__ x,
                                               const float* __restrict__ gamma,
                                               float* __restrict__ out) {
  constexpr int LDK = 72;  // 64 + 8 pad: <=2-way bank aliasing on frag reads
  __shared__ short As[128 * LDK];  // v tile   [cc][k]
  __shared__ short Bs[128 * LDK];  // att tile [m][k]
  const int tid  = threadIdx.x;
  const int b    = blockIdx.z;
  const int cc0  = blockIdx.x * 128;
  const int m0   = blockIdx.y * 128;
  const int wid  = tid >> 6, lane = tid & 63;
  const int wcc  = (wid >> 1) * 64;
  const int wm   = (wid & 1) * 64;
  const int lrow = lane & 15, quad = lane >> 4;
  floatx4 acc[4][4] = {};
  const unsigned short* vsrc = v   + ((size_t)b * 512 + cc0) * Lc;
  const unsigned short* asrc = att + ((size_t)b * Lc + m0) * Lc;
  for (int k0 = 0; k0 < Lc; k0 += 64) {
    short8 ar[4], br[4];
#pragma unroll
    for (int rnd = 0; rnd < 4; ++rnd) {
      const int idx = rnd * 256 + tid;
      const int row = idx >> 3, ch = idx & 7;
      ar[rnd] = *(const short8*)(vsrc + (size_t)row * Lc + k0 + ch * 8);
      br[rnd] = *(const short8*)(asrc + (size_t)row * Lc + k0 + ch * 8);
    }
    __syncthreads();
#pragma unroll
    for (int rnd = 0; rnd < 4; ++rnd) {
      const int idx = rnd * 256 + tid;
      const int row = idx >> 3, ch = idx & 7;
      *(short8*)&As[row * LDK + ch * 8] = ar[rnd];
      *(short8*)&Bs[row * LDK + ch * 8] = br[rnd];
    }
    __syncthreads();
#pragma unroll
    for (int kk = 0; kk < 64; kk += 32) {
      short8 af[4], bf[4];
#pragma unroll
      for (int i = 0; i < 4; ++i)
        af[i] = *(const short8*)&As[(wcc + i * 16 + lrow) * LDK + kk + quad * 8];
#pragma unroll
      for (int j = 0; j < 4; ++j)
        bf[j] = *(const short8*)&Bs[(wm + j * 16 + lrow) * LDK + kk + quad * 8];
#pragma unroll
      for (int i = 0; i < 4; ++i)
#pragma unroll
        for (int j = 0; j < 4; ++j)
          acc[i][j] = __builtin_amdgcn_mfma_f32_16x16x32_bf16(af[i], bf[j], acc[i][j], 0, 0, 0);
    }
  }
  const float gm = gamma[0];
  float svj[4];
#pragma unroll
  for (int j = 0; j < 4; ++j)
    svj[j] = gm * Sinv[(size_t)b * Lc + m0 + wm + j * 16 + lrow];
#pragma unroll
  for (int i = 0; i < 4; ++i) {
    const int ccb = cc0 + wcc + i * 16 + quad * 4;
#pragma unroll
    for (int j = 0; j < 4; ++j) {
      const int m = m0 + wm + j * 16 + lrow;
#pragma unroll
      for (int rg = 0; rg < 4; ++rg) {
        const int cc   = ccb + rg;
        const int comp = cc >> 8, c = cc & 255;
        const size_t idx = (((size_t)comp * Bc + b) * CGc + c) * Lc + m;
        out[idx] = svj[j] * acc[i][j][rg] + x[idx];
      }
    }
  }
}

// ---------------------------------------------------------------------------
extern "C" void kernel_launch(void* const* d_in, const int* in_sizes, int n_in,
                              void* d_out, int out_size, void* d_ws, size_t ws_size,
                              hipStream_t stream) {
  const float* x     = (const float*)d_in[0];
  const float* wq    = (const float*)d_in[1];
  const float* wk    = (const float*)d_in[2];
  const float* wv    = (const float*)d_in[3];
  const float* gamma = (const float*)d_in[4];
  float* out = (float*)d_out;

  // Workspace (fp32 then bf16 blocks; ~74 MB total):
  float* q    = (float*)d_ws;                    // 2*4096*16
  float* kk   = q    + (size_t)Bc * Lc * 16;     // 2*4096*16
  float* wvT  = kk   + (size_t)Bc * Lc * 16;     // 2*256*256
  float* Mrow = wvT  + (size_t)2 * CGc * CGc;    // 2*4096
  float* Sinv = Mrow + (size_t)Bc * Lc;          // 2*4096
  unsigned short* vbf = (unsigned short*)(Sinv + (size_t)Bc * Lc);  // 2*512*4096
  unsigned short* att = vbf + (size_t)Bc * 512 * Lc;                // 2*4096*4096

  wv_transpose<<<dim3((2 * CGc * CGc) / 256), 256, 0, stream>>>(wv, wvT);
  qk_proj<<<dim3(Lc / 256, Bc, 2), 256, 0, stream>>>(x, wq, wk, q, kk);
  v_proj<<<dim3(Lc / 64, CGc / 64, Bc), 256, 0, stream>>>(x, wvT, vbf);
  softmax_max<<<dim3(Lc / 16, Bc), 256, 0, stream>>>(q, kk, Mrow);
  att_exp<<<dim3(Lc / 16, Bc), 256, 0, stream>>>(q, kk, Mrow, att, Sinv);
  pv_gemm<<<dim3(512 / 128, Lc / 128, Bc), 256, 0, stream>>>(vbf, att, Sinv, x, gamma, out);
}

// Round 5
// 350.969 us; speedup vs baseline: 3.4935x; 1.1360x over previous
//
#include <hip/hip_runtime.h>
#include <cstdint>

// Shapes (fixed by the problem): B=2, C=64, G=4 -> CG=256, DQK=8, L=64*64=4096
constexpr int Bc  = 2;
constexpr int CGc = 256;
constexpr int Dc  = 8;
constexpr int Lc  = 4096;

typedef __attribute__((ext_vector_type(8))) short short8;
typedef __attribute__((ext_vector_type(4))) float floatx4;

__device__ inline unsigned short f2bf(float f) {
  union { float f; unsigned u; } v; v.f = f;
  unsigned r = v.u + 0x7fffu + ((v.u >> 16) & 1u);
  return (unsigned short)(r >> 16);
}

// ---------------------------------------------------------------------------
// Phase -1: zero Mrow(8192) + Ssum(8192) — contiguous 16384 floats.
// (ws is re-poisoned to 0xAA before every timed call; atomics need 0 init.)
// ---------------------------------------------------------------------------
__global__ __launch_bounds__(256) void init_stats(float* __restrict__ p) {
  p[blockIdx.x * 256 + threadIdx.x] = 0.f;
}

// ---------------------------------------------------------------------------
// Phase 0: transpose wv (2,CG,CG) [o][cin] -> wvT [comp][cin][o].
// ---------------------------------------------------------------------------
__global__ __launch_bounds__(256) void wv_transpose(const float* __restrict__ wv,
                                                    float* __restrict__ wvT) {
  const int i    = blockIdx.x * 256 + threadIdx.x;
  const int comp = i >> 16;
  const int rem  = i & 65535;
  const int cin  = rem >> 8;
  const int c    = rem & 255;
  wvT[i] = wv[(size_t)(comp * CGc + c) * CGc + cin];
}

// ---------------------------------------------------------------------------
// Phase 1: complex Q AND K projections in one pass (x read once, fp32).
// Thread = (m, d): 32 m x 8 d per block; 4 independent accumulator chains.
// grid (L/32, B) = 256 blocks.
// ---------------------------------------------------------------------------
__global__ __launch_bounds__(256) void qk_proj(const float* __restrict__ x,
                                               const float* __restrict__ wq,
                                               const float* __restrict__ wk,
                                               float* __restrict__ qout,
                                               float* __restrict__ kout) {
  __shared__ float ws[4 * Dc * CGc];  // 32 KB: wq_r | wq_i | wk_r | wk_i
  const int tid = threadIdx.x;
  const int b   = blockIdx.y;
  for (int i = tid; i < 2 * Dc * CGc; i += 256) {
    ws[i]                 = wq[i];
    ws[2 * Dc * CGc + i]  = wk[i];
  }
  __syncthreads();
  const int d  = tid >> 5;   // 0..7
  const int ml = tid & 31;   // 0..31
  const int m  = blockIdx.x * 32 + ml;
  const float* xr = x + ((size_t)(0 * Bc + b) * CGc) * Lc + m;
  const float* xi = x + ((size_t)(1 * Bc + b) * CGc) * Lc + m;
  const float* wqr = ws + d * CGc;
  const float* wqi = ws + (Dc + d) * CGc;
  const float* wkr = ws + 2 * Dc * CGc + d * CGc;
  const float* wki = ws + 2 * Dc * CGc + (Dc + d) * CGc;
  float qer = 0.f, qei = 0.f, ker = 0.f, kei = 0.f;
#pragma unroll 4
  for (int cin = 0; cin < CGc; ++cin) {
    const float vr = xr[(size_t)cin * Lc];
    const float vi = xi[(size_t)cin * Lc];
    const float a1 = wqr[cin], b1 = wqi[cin];
    qer += a1 * vr - b1 * vi;
    qei += a1 * vi + b1 * vr;
    const float a2 = wkr[cin], b2 = wki[cin];
    ker += a2 * vr - b2 * vi;
    kei += a2 * vi + b2 * vr;
  }
  float* qp = qout + ((size_t)b * Lc + m) * 16;
  qp[d]     = qer;
  qp[8 + d] = qei;
  float* kp = kout + ((size_t)b * Lc + m) * 16;
  kp[d]     = ker;
  kp[8 + d] = kei;
}

// ---------------------------------------------------------------------------
// Phase 2: complex V projection, bf16, CC-MAJOR: v[b][cc][l]. No LDS/barriers.
// ---------------------------------------------------------------------------
__global__ __launch_bounds__(256) void v_proj(const float* __restrict__ x,
                                              const float* __restrict__ wvT,
                                              unsigned short* __restrict__ vbf) {
  const int tid = threadIdx.x;
  const int wv  = __builtin_amdgcn_readfirstlane(tid >> 6);
  const int lt  = tid & 63;
  const int b   = blockIdx.z;
  const int c0  = blockIdx.y * 64 + wv * 16;
  const int l   = blockIdx.x * 64 + lt;
  const float* xr = x + ((size_t)(0 * Bc + b) * CGc) * Lc + l;
  const float* xi = x + ((size_t)(1 * Bc + b) * CGc) * Lc + l;
  float vr[16] = {}, vi[16] = {};
#pragma unroll 2
  for (int cin = 0; cin < CGc; ++cin) {
    const float xrv = xr[(size_t)cin * Lc];
    const float xiv = xi[(size_t)cin * Lc];
    const float* wrp = wvT + (size_t)cin * CGc + c0;
    const float* wip = wvT + (size_t)(CGc + cin) * CGc + c0;
#pragma unroll
    for (int ci = 0; ci < 16; ++ci) {
      const float wr = wrp[ci], wi = wip[ci];
      vr[ci] = fmaf(wr, xrv, vr[ci]);
      vr[ci] = fmaf(-wi, xiv, vr[ci]);
      vi[ci] = fmaf(wr, xiv, vi[ci]);
      vi[ci] = fmaf(wi, xrv, vi[ci]);
    }
  }
#pragma unroll
  for (int ci = 0; ci < 16; ++ci) {
    vbf[((size_t)b * 512 + (c0 + ci)) * Lc + l]       = f2bf(vr[ci]);
    vbf[((size_t)b * 512 + 256 + (c0 + ci)) * Lc + l] = f2bf(vi[ci]);
  }
}

// ---------------------------------------------------------------------------
// Phase 3: row max of E[b,m,l] = |q(m).k(l)|^2, l-split x4 for occupancy.
// E >= 0, so float max == unsigned-int max: wave butterfly then atomicMax.
// grid (L/16, 4, B); wave = 4 rows x 1024 l.
// ---------------------------------------------------------------------------
__global__ __launch_bounds__(256) void softmax_max(const float* __restrict__ q,
                                                   const float* __restrict__ kg,
                                                   float* __restrict__ Mrow) {
  const int tid = threadIdx.x;
  const int wv  = __builtin_amdgcn_readfirstlane(tid >> 6);
  const int lt  = tid & 63;
  const int b   = blockIdx.z;
  const int mb  = blockIdx.x * 16 + wv * 4;
  const int lbeg = blockIdx.y * (Lc / 4);
  float qv[4][16];
#pragma unroll
  for (int j = 0; j < 4; ++j)
#pragma unroll
    for (int t = 0; t < 16; ++t) qv[j][t] = q[((size_t)b * Lc + mb + j) * 16 + t];
  float mx[4] = {0.f, 0.f, 0.f, 0.f};  // E >= 0
  const float* kbase = kg + ((size_t)b * Lc + lt) * 16;
#pragma unroll 2
  for (int l0 = lbeg; l0 < lbeg + Lc / 4; l0 += 64) {
    const float4 ka = *(const float4*)(kbase + (size_t)l0 * 16 + 0);
    const float4 kb = *(const float4*)(kbase + (size_t)l0 * 16 + 4);
    const float4 kc = *(const float4*)(kbase + (size_t)l0 * 16 + 8);
    const float4 kd = *(const float4*)(kbase + (size_t)l0 * 16 + 12);
    const float k0[16] = {ka.x, ka.y, ka.z, ka.w, kb.x, kb.y, kb.z, kb.w,
                          kc.x, kc.y, kc.z, kc.w, kd.x, kd.y, kd.z, kd.w};
#pragma unroll
    for (int j = 0; j < 4; ++j) {
      float er = 0.f, ei = 0.f;
#pragma unroll
      for (int d = 0; d < 8; ++d) {
        er += qv[j][d] * k0[d] - qv[j][8 + d] * k0[8 + d];
        ei += qv[j][d] * k0[8 + d] + qv[j][8 + d] * k0[d];
      }
      mx[j] = fmaxf(mx[j], er * er + ei * ei);
    }
  }
#pragma unroll
  for (int j = 0; j < 4; ++j) {
#pragma unroll
    for (int off = 32; off > 0; off >>= 1) mx[j] = fmaxf(mx[j], __shfl_xor(mx[j], off));
    if (lt == 0)
      atomicMax((unsigned*)&Mrow[(size_t)b * Lc + mb + j], __float_as_uint(mx[j]));
  }
}

// ---------------------------------------------------------------------------
// Phase 4: att[m][l] = bf16(__expf(E-M)) (unnormalized) + partial row sums
// atomicAdd'ed into Ssum. Same l-split x4 structure.
// ---------------------------------------------------------------------------
__global__ __launch_bounds__(256) void att_exp(const float* __restrict__ q,
                                               const float* __restrict__ kg,
                                               const float* __restrict__ Mrow,
                                               unsigned short* __restrict__ att,
                                               float* __restrict__ Ssum) {
  const int tid = threadIdx.x;
  const int wv  = __builtin_amdgcn_readfirstlane(tid >> 6);
  const int lt  = tid & 63;
  const int b   = blockIdx.z;
  const int mb  = blockIdx.x * 16 + wv * 4;
  const int lbeg = blockIdx.y * (Lc / 4);
  float qv[4][16], Mv[4], sum[4] = {};
#pragma unroll
  for (int j = 0; j < 4; ++j) {
#pragma unroll
    for (int t = 0; t < 16; ++t) qv[j][t] = q[((size_t)b * Lc + mb + j) * 16 + t];
    Mv[j] = Mrow[(size_t)b * Lc + mb + j];
  }
  const float* kbase = kg + ((size_t)b * Lc + lt) * 16;
  unsigned short* arow = att + ((size_t)b * Lc + mb) * Lc + lt;
#pragma unroll 2
  for (int l0 = lbeg; l0 < lbeg + Lc / 4; l0 += 64) {
    const float4 ka = *(const float4*)(kbase + (size_t)l0 * 16 + 0);
    const float4 kb = *(const float4*)(kbase + (size_t)l0 * 16 + 4);
    const float4 kc = *(const float4*)(kbase + (size_t)l0 * 16 + 8);
    const float4 kd = *(const float4*)(kbase + (size_t)l0 * 16 + 12);
    const float k0[16] = {ka.x, ka.y, ka.z, ka.w, kb.x, kb.y, kb.z, kb.w,
                          kc.x, kc.y, kc.z, kc.w, kd.x, kd.y, kd.z, kd.w};
#pragma unroll
    for (int j = 0; j < 4; ++j) {
      float er = 0.f, ei = 0.f;
#pragma unroll
      for (int d = 0; d < 8; ++d) {
        er += qv[j][d] * k0[d] - qv[j][8 + d] * k0[8 + d];
        ei += qv[j][d] * k0[8 + d] + qv[j][8 + d] * k0[d];
      }
      const float wgt = __expf(er * er + ei * ei - Mv[j]);
      sum[j] += wgt;
      arow[(size_t)j * Lc + l0] = f2bf(wgt);
    }
  }
#pragma unroll
  for (int j = 0; j < 4; ++j) {
#pragma unroll
    for (int off = 32; off > 0; off >>= 1) sum[j] += __shfl_xor(sum[j], off);
    if (lt == 0) atomicAdd(&Ssum[(size_t)b * Lc + mb + j], sum[j]);
  }
}

// ---------------------------------------------------------------------------
// Phase 5: PV GEMM via bf16 MFMA.  C[cc][m] = sum_l v[cc][l] * att[m][l].
// Tile 128cc x 64m -> 512 blocks (2/CU, 8 waves/CU). 4 waves of 64cc x 32m.
// Grid cc-fastest: 4 consecutive blocks share the att m-panel (L2 reuse).
// Epilogue: out = (gamma/Ssum[m]) * acc + x.
// ---------------------------------------------------------------------------
__global__ __launch_bounds__(256) void pv_gemm(const unsigned short* __restrict__ v,
                                               const unsigned short* __restrict__ att,
                                               const float* __restrict__ Ssum,
                                               const float* __restrict__ x,
                                               const float* __restrict__ gamma,
                                               float* __restrict__ out) {
  constexpr int LDK = 72;  // 64 + 8 pad: <=2-way bank aliasing on frag reads
  __shared__ short As[128 * LDK];  // v tile   [cc][k]
  __shared__ short Bs[64 * LDK];   // att tile [m][k]
  const int tid  = threadIdx.x;
  const int b    = blockIdx.z;
  const int cc0  = blockIdx.x * 128;
  const int m0   = blockIdx.y * 64;
  const int wid  = tid >> 6, lane = tid & 63;
  const int wcc  = (wid >> 1) * 64;
  const int wm   = (wid & 1) * 32;
  const int lrow = lane & 15, quad = lane >> 4;
  floatx4 acc[4][2] = {};
  const unsigned short* vsrc = v   + ((size_t)b * 512 + cc0) * Lc;
  const unsigned short* asrc = att + ((size_t)b * Lc + m0) * Lc;
  for (int k0 = 0; k0 < Lc; k0 += 64) {
    short8 ar[4], br[2];
#pragma unroll
    for (int rnd = 0; rnd < 4; ++rnd) {
      const int idx = rnd * 256 + tid;
      const int row = idx >> 3, ch = idx & 7;
      ar[rnd] = *(const short8*)(vsrc + (size_t)row * Lc + k0 + ch * 8);
    }
#pragma unroll
    for (int rnd = 0; rnd < 2; ++rnd) {
      const int idx = rnd * 256 + tid;
      const int row = idx >> 3, ch = idx & 7;
      br[rnd] = *(const short8*)(asrc + (size_t)row * Lc + k0 + ch * 8);
    }
    __syncthreads();
#pragma unroll
    for (int rnd = 0; rnd < 4; ++rnd) {
      const int idx = rnd * 256 + tid;
      const int row = idx >> 3, ch = idx & 7;
      *(short8*)&As[row * LDK + ch * 8] = ar[rnd];
    }
#pragma unroll
    for (int rnd = 0; rnd < 2; ++rnd) {
      const int idx = rnd * 256 + tid;
      const int row = idx >> 3, ch = idx & 7;
      *(short8*)&Bs[row * LDK + ch * 8] = br[rnd];
    }
    __syncthreads();
#pragma unroll
    for (int kk = 0; kk < 64; kk += 32) {
      short8 af[4], bf[2];
#pragma unroll
      for (int i = 0; i < 4; ++i)
        af[i] = *(const short8*)&As[(wcc + i * 16 + lrow) * LDK + kk + quad * 8];
#pragma unroll
      for (int j = 0; j < 2; ++j)
        bf[j] = *(const short8*)&Bs[(wm + j * 16 + lrow) * LDK + kk + quad * 8];
#pragma unroll
      for (int i = 0; i < 4; ++i)
#pragma unroll
        for (int j = 0; j < 2; ++j)
          acc[i][j] = __builtin_amdgcn_mfma_f32_16x16x32_bf16(af[i], bf[j], acc[i][j], 0, 0, 0);
    }
  }
  const float gm = gamma[0];
  float svj[2];
#pragma unroll
  for (int j = 0; j < 2; ++j)
    svj[j] = gm / Ssum[(size_t)b * Lc + m0 + wm + j * 16 + lrow];
#pragma unroll
  for (int i = 0; i < 4; ++i) {
    const int ccb = cc0 + wcc + i * 16 + quad * 4;
#pragma unroll
    for (int j = 0; j < 2; ++j) {
      const int m = m0 + wm + j * 16 + lrow;
#pragma unroll
      for (int rg = 0; rg < 4; ++rg) {
        const int cc   = ccb + rg;
        const int comp = cc >> 8, c = cc & 255;
        const size_t idx = (((size_t)comp * Bc + b) * CGc + c) * Lc + m;
        out[idx] = svj[j] * acc[i][j][rg] + x[idx];
      }
    }
  }
}

// ---------------------------------------------------------------------------
extern "C" void kernel_launch(void* const* d_in, const int* in_sizes, int n_in,
                              void* d_out, int out_size, void* d_ws, size_t ws_size,
                              hipStream_t stream) {
  const float* x     = (const float*)d_in[0];
  const float* wq    = (const float*)d_in[1];
  const float* wk    = (const float*)d_in[2];
  const float* wv    = (const float*)d_in[3];
  const float* gamma = (const float*)d_in[4];
  float* out = (float*)d_out;

  // Workspace (fp32 then bf16 blocks; ~74 MB total):
  float* q    = (float*)d_ws;                    // 2*4096*16
  float* kk   = q    + (size_t)Bc * Lc * 16;     // 2*4096*16
  float* wvT  = kk   + (size_t)Bc * Lc * 16;     // 2*256*256
  float* Mrow = wvT  + (size_t)2 * CGc * CGc;    // 2*4096   } contiguous: init
  float* Ssum = Mrow + (size_t)Bc * Lc;          // 2*4096   } zeroes both
  unsigned short* vbf = (unsigned short*)(Ssum + (size_t)Bc * Lc);  // 2*512*4096
  unsigned short* att = vbf + (size_t)Bc * 512 * Lc;                // 2*4096*4096

  init_stats<<<dim3((2 * Bc * Lc) / 256), 256, 0, stream>>>(Mrow);
  wv_transpose<<<dim3((2 * CGc * CGc) / 256), 256, 0, stream>>>(wv, wvT);
  qk_proj<<<dim3(Lc / 32, Bc), 256, 0, stream>>>(x, wq, wk, q, kk);
  v_proj<<<dim3(Lc / 64, CGc / 64, Bc), 256, 0, stream>>>(x, wvT, vbf);
  softmax_max<<<dim3(Lc / 16, 4, Bc), 256, 0, stream>>>(q, kk, Mrow);
  att_exp<<<dim3(Lc / 16, 4, Bc), 256, 0, stream>>>(q, kk, Mrow, att, Ssum);
  pv_gemm<<<dim3(512 / 128, Lc / 64, Bc), 256, 0, stream>>>(vbf, att, Ssum, x, gamma, out);
}

// Round 6
// 325.403 us; speedup vs baseline: 3.7679x; 1.0786x over previous
//
#include <hip/hip_runtime.h>
#include <cstdint>

// Shapes (fixed by the problem): B=2, C=64, G=4 -> CG=256, DQK=8, L=64*64=4096
constexpr int Bc  = 2;
constexpr int CGc = 256;
constexpr int Dc  = 8;
constexpr int Lc  = 4096;

typedef __attribute__((ext_vector_type(8))) short short8;
typedef __attribute__((ext_vector_type(4))) float floatx4;

__device__ inline unsigned short f2bf(float f) {
  union { float f; unsigned u; } v; v.f = f;
  unsigned r = v.u + 0x7fffu + ((v.u >> 16) & 1u);
  return (unsigned short)(r >> 16);
}
// rounded bf16 kept in HIGH half (for packing two into a dword)
__device__ inline unsigned f2bf_hi(float f) {
  union { float f; unsigned u; } v; v.f = f;
  return (v.u + 0x7fffu + ((v.u >> 16) & 1u)) & 0xFFFF0000u;
}
__device__ inline float rdfl(float x) {
  return __uint_as_float(__builtin_amdgcn_readfirstlane(__float_as_uint(x)));
}

// ---------------------------------------------------------------------------
// Phase -1: zero Mrow(8192) + Ssum(8192) — contiguous 16384 floats.
// ---------------------------------------------------------------------------
__global__ __launch_bounds__(256) void init_stats(float* __restrict__ p) {
  p[blockIdx.x * 256 + threadIdx.x] = 0.f;
}

// ---------------------------------------------------------------------------
// Phase 0: transpose wv (2,CG,CG) [o][cin] -> wvT [comp][cin][o].
// ---------------------------------------------------------------------------
__global__ __launch_bounds__(256) void wv_transpose(const float* __restrict__ wv,
                                                    float* __restrict__ wvT) {
  const int i    = blockIdx.x * 256 + threadIdx.x;
  const int comp = i >> 16;
  const int rem  = i & 65535;
  const int cin  = rem >> 8;
  const int c    = rem & 255;
  wvT[i] = wv[(size_t)(comp * CGc + c) * CGc + cin];
}

// ---------------------------------------------------------------------------
// Phase 1: complex Q AND K projections in one pass (x read once, fp32).
// Thread = (m, d): 32 m x 8 d per block; explicit fmaf chains.
// ---------------------------------------------------------------------------
__global__ __launch_bounds__(256) void qk_proj(const float* __restrict__ x,
                                               const float* __restrict__ wq,
                                               const float* __restrict__ wk,
                                               float* __restrict__ qout,
                                               float* __restrict__ kout) {
  __shared__ float ws[4 * Dc * CGc];  // 32 KB: wq_r | wq_i | wk_r | wk_i
  const int tid = threadIdx.x;
  const int b   = blockIdx.y;
  for (int i = tid; i < 2 * Dc * CGc; i += 256) {
    ws[i]                 = wq[i];
    ws[2 * Dc * CGc + i]  = wk[i];
  }
  __syncthreads();
  const int d  = tid >> 5;   // 0..7
  const int ml = tid & 31;   // 0..31
  const int m  = blockIdx.x * 32 + ml;
  const float* xr = x + ((size_t)(0 * Bc + b) * CGc) * Lc + m;
  const float* xi = x + ((size_t)(1 * Bc + b) * CGc) * Lc + m;
  const float* wqr = ws + d * CGc;
  const float* wqi = ws + (Dc + d) * CGc;
  const float* wkr = ws + 2 * Dc * CGc + d * CGc;
  const float* wki = ws + 2 * Dc * CGc + (Dc + d) * CGc;
  float qer = 0.f, qei = 0.f, ker = 0.f, kei = 0.f;
#pragma unroll 4
  for (int cin = 0; cin < CGc; ++cin) {
    const float vr = xr[(size_t)cin * Lc];
    const float vi = xi[(size_t)cin * Lc];
    const float a1 = wqr[cin], b1 = wqi[cin];
    qer = fmaf(a1, vr, qer); qer = fmaf(-b1, vi, qer);
    qei = fmaf(a1, vi, qei); qei = fmaf(b1, vr, qei);
    const float a2 = wkr[cin], b2 = wki[cin];
    ker = fmaf(a2, vr, ker); ker = fmaf(-b2, vi, ker);
    kei = fmaf(a2, vi, kei); kei = fmaf(b2, vr, kei);
  }
  float* qp = qout + ((size_t)b * Lc + m) * 16;
  qp[d]     = qer;
  qp[8 + d] = qei;
  float* kp = kout + ((size_t)b * Lc + m) * 16;
  kp[d]     = ker;
  kp[8 + d] = kei;
}

// ---------------------------------------------------------------------------
// Phase 2: complex V projection, bf16, CC-MAJOR: v[b][cc][l]. No LDS/barriers.
// ---------------------------------------------------------------------------
__global__ __launch_bounds__(256) void v_proj(const float* __restrict__ x,
                                              const float* __restrict__ wvT,
                                              unsigned short* __restrict__ vbf) {
  const int tid = threadIdx.x;
  const int wv  = __builtin_amdgcn_readfirstlane(tid >> 6);
  const int lt  = tid & 63;
  const int b   = blockIdx.z;
  const int c0  = blockIdx.y * 64 + wv * 16;
  const int l   = blockIdx.x * 64 + lt;
  const float* xr = x + ((size_t)(0 * Bc + b) * CGc) * Lc + l;
  const float* xi = x + ((size_t)(1 * Bc + b) * CGc) * Lc + l;
  float vr[16] = {}, vi[16] = {};
#pragma unroll 2
  for (int cin = 0; cin < CGc; ++cin) {
    const float xrv = xr[(size_t)cin * Lc];
    const float xiv = xi[(size_t)cin * Lc];
    const float* wrp = wvT + (size_t)cin * CGc + c0;
    const float* wip = wvT + (size_t)(CGc + cin) * CGc + c0;
#pragma unroll
    for (int ci = 0; ci < 16; ++ci) {
      const float wr = wrp[ci], wi = wip[ci];
      vr[ci] = fmaf(wr, xrv, vr[ci]);
      vr[ci] = fmaf(-wi, xiv, vr[ci]);
      vi[ci] = fmaf(wr, xiv, vi[ci]);
      vi[ci] = fmaf(wi, xrv, vi[ci]);
    }
  }
#pragma unroll
  for (int ci = 0; ci < 16; ++ci) {
    vbf[((size_t)b * 512 + (c0 + ci)) * Lc + l]       = f2bf(vr[ci]);
    vbf[((size_t)b * 512 + 256 + (c0 + ci)) * Lc + l] = f2bf(vi[ci]);
  }
}

// ---------------------------------------------------------------------------
// Phase 3: row max of E[b,m,l] = |q(m).k(l)|^2, l-split x4, q/M in SGPRs,
// explicit fmaf chains.  E >= 0 so float max == uint max -> atomicMax.
// ---------------------------------------------------------------------------
__global__ __launch_bounds__(256) void softmax_max(const float* __restrict__ q,
                                                   const float* __restrict__ kg,
                                                   float* __restrict__ Mrow) {
  const int tid = threadIdx.x;
  const int wv  = __builtin_amdgcn_readfirstlane(tid >> 6);
  const int lt  = tid & 63;
  const int b   = blockIdx.z;
  const int mb  = blockIdx.x * 16 + wv * 4;
  const int lbeg = blockIdx.y * (Lc / 4);
  float qv[4][16];
#pragma unroll
  for (int j = 0; j < 4; ++j) {
    const float* qp = q + ((size_t)b * Lc + mb + j) * 16;
#pragma unroll
    for (int t = 0; t < 16; ++t) qv[j][t] = rdfl(qp[t]);
  }
  float mx[4] = {0.f, 0.f, 0.f, 0.f};  // E >= 0
  const float* kbase = kg + (size_t)b * Lc * 16;
#pragma unroll 2
  for (int l0 = lbeg; l0 < lbeg + Lc / 4; l0 += 64) {
    const float* kp = kbase + (size_t)(l0 + lt) * 16;
    const float4 ka = *(const float4*)(kp + 0);
    const float4 kb = *(const float4*)(kp + 4);
    const float4 kc = *(const float4*)(kp + 8);
    const float4 kd = *(const float4*)(kp + 12);
    const float k0[16] = {ka.x, ka.y, ka.z, ka.w, kb.x, kb.y, kb.z, kb.w,
                          kc.x, kc.y, kc.z, kc.w, kd.x, kd.y, kd.z, kd.w};
#pragma unroll
    for (int j = 0; j < 4; ++j) {
      float er = qv[j][0] * k0[0];
      float ei = qv[j][0] * k0[8];
      er = fmaf(-qv[j][8], k0[8], er);
      ei = fmaf(qv[j][8], k0[0], ei);
#pragma unroll
      for (int d = 1; d < 8; ++d) {
        er = fmaf(qv[j][d], k0[d], er);
        er = fmaf(-qv[j][8 + d], k0[8 + d], er);
        ei = fmaf(qv[j][d], k0[8 + d], ei);
        ei = fmaf(qv[j][8 + d], k0[d], ei);
      }
      float e = er * er;
      e = fmaf(ei, ei, e);
      mx[j] = fmaxf(mx[j], e);
    }
  }
#pragma unroll
  for (int j = 0; j < 4; ++j) {
#pragma unroll
    for (int off = 32; off > 0; off >>= 1) mx[j] = fmaxf(mx[j], __shfl_xor(mx[j], off));
    if (lt == 0)
      atomicMax((unsigned*)&Mrow[(size_t)b * Lc + mb + j], __float_as_uint(mx[j]));
  }
}

// ---------------------------------------------------------------------------
// Phase 4: att[m][l] = bf16(__expf(E-M)) (unnormalized) + partial row sums.
// 2 l per lane -> packed bf16x2 dword stores; q/M in SGPRs; fmaf chains.
// ---------------------------------------------------------------------------
__global__ __launch_bounds__(256) void att_exp(const float* __restrict__ q,
                                               const float* __restrict__ kg,
                                               const float* __restrict__ Mrow,
                                               unsigned* __restrict__ att,
                                               float* __restrict__ Ssum) {
  const int tid = threadIdx.x;
  const int wv  = __builtin_amdgcn_readfirstlane(tid >> 6);
  const int lt  = tid & 63;
  const int b   = blockIdx.z;
  const int mb  = blockIdx.x * 16 + wv * 4;
  const int lbeg = blockIdx.y * (Lc / 4);
  float qv[4][16], Mv[4], sum[4] = {};
#pragma unroll
  for (int j = 0; j < 4; ++j) {
    const float* qp = q + ((size_t)b * Lc + mb + j) * 16;
#pragma unroll
    for (int t = 0; t < 16; ++t) qv[j][t] = rdfl(qp[t]);
    Mv[j] = rdfl(Mrow[(size_t)b * Lc + mb + j]);
  }
  const float* kbase = kg + (size_t)b * Lc * 16;
  unsigned* arow = att + ((size_t)b * Lc + mb) * (Lc / 2) + lt;
  for (int l0 = lbeg; l0 < lbeg + Lc / 4; l0 += 128) {
    const float* kp = kbase + (size_t)(l0 + 2 * lt) * 16;
    const float4 ka = *(const float4*)(kp + 0);
    const float4 kb = *(const float4*)(kp + 4);
    const float4 kc = *(const float4*)(kp + 8);
    const float4 kd = *(const float4*)(kp + 12);
    const float4 ke = *(const float4*)(kp + 16);
    const float4 kf = *(const float4*)(kp + 20);
    const float4 kgv = *(const float4*)(kp + 24);
    const float4 kh = *(const float4*)(kp + 28);
    const float k0[16] = {ka.x, ka.y, ka.z, ka.w, kb.x, kb.y, kb.z, kb.w,
                          kc.x, kc.y, kc.z, kc.w, kd.x, kd.y, kd.z, kd.w};
    const float k1[16] = {ke.x, ke.y, ke.z, ke.w, kf.x, kf.y, kf.z, kf.w,
                          kgv.x, kgv.y, kgv.z, kgv.w, kh.x, kh.y, kh.z, kh.w};
#pragma unroll
    for (int j = 0; j < 4; ++j) {
      float er0 = qv[j][0] * k0[0], ei0 = qv[j][0] * k0[8];
      float er1 = qv[j][0] * k1[0], ei1 = qv[j][0] * k1[8];
      er0 = fmaf(-qv[j][8], k0[8], er0); ei0 = fmaf(qv[j][8], k0[0], ei0);
      er1 = fmaf(-qv[j][8], k1[8], er1); ei1 = fmaf(qv[j][8], k1[0], ei1);
#pragma unroll
      for (int d = 1; d < 8; ++d) {
        er0 = fmaf(qv[j][d], k0[d], er0);
        er0 = fmaf(-qv[j][8 + d], k0[8 + d], er0);
        ei0 = fmaf(qv[j][d], k0[8 + d], ei0);
        ei0 = fmaf(qv[j][8 + d], k0[d], ei0);
        er1 = fmaf(qv[j][d], k1[d], er1);
        er1 = fmaf(-qv[j][8 + d], k1[8 + d], er1);
        ei1 = fmaf(qv[j][d], k1[8 + d], ei1);
        ei1 = fmaf(qv[j][8 + d], k1[d], ei1);
      }
      float e0 = er0 * er0; e0 = fmaf(ei0, ei0, e0);
      float e1 = er1 * er1; e1 = fmaf(ei1, ei1, e1);
      const float w0 = __expf(e0 - Mv[j]);
      const float w1 = __expf(e1 - Mv[j]);
      sum[j] += w0 + w1;
      arow[(size_t)j * (Lc / 2) + (l0 >> 1)] =
          (f2bf_hi(w0) >> 16) | f2bf_hi(w1);
    }
  }
#pragma unroll
  for (int j = 0; j < 4; ++j) {
#pragma unroll
    for (int off = 32; off > 0; off >>= 1) sum[j] += __shfl_xor(sum[j], off);
    if (lt == 0) atomicAdd(&Ssum[(size_t)b * Lc + mb + j], sum[j]);
  }
}

// ---------------------------------------------------------------------------
// Phase 5: PV GEMM via bf16 MFMA.  C[cc][m] = sum_l v[cc][l] * att[m][l].
// Tile 128cc x 64m -> 512 blocks; grid cc-fastest for att L2 reuse.
// Epilogue: out = (gamma/Ssum[m]) * acc + x.
// ---------------------------------------------------------------------------
__global__ __launch_bounds__(256) void pv_gemm(const unsigned short* __restrict__ v,
                                               const unsigned short* __restrict__ att,
                                               const float* __restrict__ Ssum,
                                               const float* __restrict__ x,
                                               const float* __restrict__ gamma,
                                               float* __restrict__ out) {
  constexpr int LDK = 72;  // 64 + 8 pad: <=2-way bank aliasing on frag reads
  __shared__ short As[128 * LDK];  // v tile   [cc][k]
  __shared__ short Bs[64 * LDK];   // att tile [m][k]
  const int tid  = threadIdx.x;
  const int b    = blockIdx.z;
  const int cc0  = blockIdx.x * 128;
  const int m0   = blockIdx.y * 64;
  const int wid  = tid >> 6, lane = tid & 63;
  const int wcc  = (wid >> 1) * 64;
  const int wm   = (wid & 1) * 32;
  const int lrow = lane & 15, quad = lane >> 4;
  floatx4 acc[4][2] = {};
  const unsigned short* vsrc = v   + ((size_t)b * 512 + cc0) * Lc;
  const unsigned short* asrc = att + ((size_t)b * Lc + m0) * Lc;
  for (int k0 = 0; k0 < Lc; k0 += 64) {
    short8 ar[4], br[2];
#pragma unroll
    for (int rnd = 0; rnd < 4; ++rnd) {
      const int idx = rnd * 256 + tid;
      const int row = idx >> 3, ch = idx & 7;
      ar[rnd] = *(const short8*)(vsrc + (size_t)row * Lc + k0 + ch * 8);
    }
#pragma unroll
    for (int rnd = 0; rnd < 2; ++rnd) {
      const int idx = rnd * 256 + tid;
      const int row = idx >> 3, ch = idx & 7;
      br[rnd] = *(const short8*)(asrc + (size_t)row * Lc + k0 + ch * 8);
    }
    __syncthreads();
#pragma unroll
    for (int rnd = 0; rnd < 4; ++rnd) {
      const int idx = rnd * 256 + tid;
      const int row = idx >> 3, ch = idx & 7;
      *(short8*)&As[row * LDK + ch * 8] = ar[rnd];
    }
#pragma unroll
    for (int rnd = 0; rnd < 2; ++rnd) {
      const int idx = rnd * 256 + tid;
      const int row = idx >> 3, ch = idx & 7;
      *(short8*)&Bs[row * LDK + ch * 8] = br[rnd];
    }
    __syncthreads();
#pragma unroll
    for (int kk = 0; kk < 64; kk += 32) {
      short8 af[4], bf[2];
#pragma unroll
      for (int i = 0; i < 4; ++i)
        af[i] = *(const short8*)&As[(wcc + i * 16 + lrow) * LDK + kk + quad * 8];
#pragma unroll
      for (int j = 0; j < 2; ++j)
        bf[j] = *(const short8*)&Bs[(wm + j * 16 + lrow) * LDK + kk + quad * 8];
#pragma unroll
      for (int i = 0; i < 4; ++i)
#pragma unroll
        for (int j = 0; j < 2; ++j)
          acc[i][j] = __builtin_amdgcn_mfma_f32_16x16x32_bf16(af[i], bf[j], acc[i][j], 0, 0, 0);
    }
  }
  const float gm = gamma[0];
  float svj[2];
#pragma unroll
  for (int j = 0; j < 2; ++j)
    svj[j] = gm / Ssum[(size_t)b * Lc + m0 + wm + j * 16 + lrow];
#pragma unroll
  for (int i = 0; i < 4; ++i) {
    const int ccb = cc0 + wcc + i * 16 + quad * 4;
#pragma unroll
    for (int j = 0; j < 2; ++j) {
      const int m = m0 + wm + j * 16 + lrow;
#pragma unroll
      for (int rg = 0; rg < 4; ++rg) {
        const int cc   = ccb + rg;
        const int comp = cc >> 8, c = cc & 255;
        const size_t idx = (((size_t)comp * Bc + b) * CGc + c) * Lc + m;
        out[idx] = svj[j] * acc[i][j][rg] + x[idx];
      }
    }
  }
}

// ---------------------------------------------------------------------------
extern "C" void kernel_launch(void* const* d_in, const int* in_sizes, int n_in,
                              void* d_out, int out_size, void* d_ws, size_t ws_size,
                              hipStream_t stream) {
  const float* x     = (const float*)d_in[0];
  const float* wq    = (const float*)d_in[1];
  const float* wk    = (const float*)d_in[2];
  const float* wv    = (const float*)d_in[3];
  const float* gamma = (const float*)d_in[4];
  float* out = (float*)d_out;

  // Workspace (fp32 then bf16 blocks; ~74 MB total):
  float* q    = (float*)d_ws;                    // 2*4096*16
  float* kk   = q    + (size_t)Bc * Lc * 16;     // 2*4096*16
  float* wvT  = kk   + (size_t)Bc * Lc * 16;     // 2*256*256
  float* Mrow = wvT  + (size_t)2 * CGc * CGc;    // 2*4096   } contiguous: init
  float* Ssum = Mrow + (size_t)Bc * Lc;          // 2*4096   } zeroes both
  unsigned short* vbf = (unsigned short*)(Ssum + (size_t)Bc * Lc);  // 2*512*4096
  unsigned short* att = vbf + (size_t)Bc * 512 * Lc;                // 2*4096*4096

  init_stats<<<dim3((2 * Bc * Lc) / 256), 256, 0, stream>>>(Mrow);
  wv_transpose<<<dim3((2 * CGc * CGc) / 256), 256, 0, stream>>>(wv, wvT);
  qk_proj<<<dim3(Lc / 32, Bc), 256, 0, stream>>>(x, wq, wk, q, kk);
  v_proj<<<dim3(Lc / 64, CGc / 64, Bc), 256, 0, stream>>>(x, wvT, vbf);
  softmax_max<<<dim3(Lc / 16, 4, Bc), 256, 0, stream>>>(q, kk, Mrow);
  att_exp<<<dim3(Lc / 16, 4, Bc), 256, 0, stream>>>(q, kk, Mrow, (unsigned*)att, Ssum);
  pv_gemm<<<dim3(512 / 128, Lc / 64, Bc), 256, 0, stream>>>(vbf, att, Ssum, x, gamma, out);
}

// Round 7
// 274.793 us; speedup vs baseline: 4.4619x; 1.1842x over previous
//
#include <hip/hip_runtime.h>
#include <cstdint>

// Shapes (fixed by the problem): B=2, C=64, G=4 -> CG=256, DQK=8, L=64*64=4096
constexpr int Bc  = 2;
constexpr int CGc = 256;
constexpr int Dc  = 8;
constexpr int Lc  = 4096;

typedef __attribute__((ext_vector_type(8))) short short8;
typedef __attribute__((ext_vector_type(4))) float floatx4;

__device__ inline unsigned short f2bf(float f) {
  union { float f; unsigned u; } v; v.f = f;
  unsigned r = v.u + 0x7fffu + ((v.u >> 16) & 1u);
  return (unsigned short)(r >> 16);
}
__device__ inline float bf2f(unsigned short h) {
  return __uint_as_float((unsigned)h << 16);
}

// ---------------------------------------------------------------------------
// Phase -1: zero Mrow(8192) + Ssum(8192) — contiguous 16384 floats.
// ---------------------------------------------------------------------------
__global__ __launch_bounds__(256) void init_stats(float* __restrict__ p) {
  p[blockIdx.x * 256 + threadIdx.x] = 0.f;
}

// ---------------------------------------------------------------------------
// Phase 0: transpose wv (2,CG,CG) [o][cin] -> wvT [comp][cin][o].
// ---------------------------------------------------------------------------
__global__ __launch_bounds__(256) void wv_transpose(const float* __restrict__ wv,
                                                    float* __restrict__ wvT) {
  const int i    = blockIdx.x * 256 + threadIdx.x;
  const int comp = i >> 16;
  const int rem  = i & 65535;
  const int cin  = rem >> 8;
  const int c    = rem & 255;
  wvT[i] = wv[(size_t)(comp * CGc + c) * CGc + cin];
}

// ---------------------------------------------------------------------------
// Phase 1: complex Q AND K projections in one pass (x read once, fp32).
// ---------------------------------------------------------------------------
__global__ __launch_bounds__(256) void qk_proj(const float* __restrict__ x,
                                               const float* __restrict__ wq,
                                               const float* __restrict__ wk,
                                               float* __restrict__ qout,
                                               float* __restrict__ kout) {
  __shared__ float ws[4 * Dc * CGc];  // 32 KB: wq_r | wq_i | wk_r | wk_i
  const int tid = threadIdx.x;
  const int b   = blockIdx.y;
  for (int i = tid; i < 2 * Dc * CGc; i += 256) {
    ws[i]                 = wq[i];
    ws[2 * Dc * CGc + i]  = wk[i];
  }
  __syncthreads();
  const int d  = tid >> 5;   // 0..7
  const int ml = tid & 31;   // 0..31
  const int m  = blockIdx.x * 32 + ml;
  const float* xr = x + ((size_t)(0 * Bc + b) * CGc) * Lc + m;
  const float* xi = x + ((size_t)(1 * Bc + b) * CGc) * Lc + m;
  const float* wqr = ws + d * CGc;
  const float* wqi = ws + (Dc + d) * CGc;
  const float* wkr = ws + 2 * Dc * CGc + d * CGc;
  const float* wki = ws + 2 * Dc * CGc + (Dc + d) * CGc;
  float qer = 0.f, qei = 0.f, ker = 0.f, kei = 0.f;
#pragma unroll 4
  for (int cin = 0; cin < CGc; ++cin) {
    const float vr = xr[(size_t)cin * Lc];
    const float vi = xi[(size_t)cin * Lc];
    const float a1 = wqr[cin], b1 = wqi[cin];
    qer = fmaf(a1, vr, qer); qer = fmaf(-b1, vi, qer);
    qei = fmaf(a1, vi, qei); qei = fmaf(b1, vr, qei);
    const float a2 = wkr[cin], b2 = wki[cin];
    ker = fmaf(a2, vr, ker); ker = fmaf(-b2, vi, ker);
    kei = fmaf(a2, vi, kei); kei = fmaf(b2, vr, kei);
  }
  float* qp = qout + ((size_t)b * Lc + m) * 16;
  qp[d]     = qer;
  qp[8 + d] = qei;
  float* kp = kout + ((size_t)b * Lc + m) * 16;
  kp[d]     = ker;
  kp[8 + d] = kei;
}

// ---------------------------------------------------------------------------
// Phase 1b: split-bf16 packing for MFMA QK^T.
//   Qcat [r][32]  = [bf16hi(q~), bf16lo(q~)]          (q~ = [qr(8), qi(8)])
//   K1hi [r][16]  = bf16hi(k~1), K1loz[r][32] = [bf16lo(k~1), zeros]
//   K2hi/K2loz     same for k~2, where k~1=[kr,-ki], k~2=[ki,kr].
// er = q~.k~1, ei = q~.k~2 ≈ hi.hi + lo.hi + hi.lo (residual ~2^-17).
// One thread per row r = b*L+m (8192 rows).
// ---------------------------------------------------------------------------
__global__ __launch_bounds__(256) void qk_pack(const float* __restrict__ q,
                                               const float* __restrict__ k,
                                               unsigned short* __restrict__ Qcat,
                                               unsigned short* __restrict__ K1hi,
                                               unsigned short* __restrict__ K1loz,
                                               unsigned short* __restrict__ K2hi,
                                               unsigned short* __restrict__ K2loz) {
  const int r = blockIdx.x * 256 + threadIdx.x;  // 0..8191
  // --- Q ---
  {
    const float* qp = q + (size_t)r * 16;
    unsigned u[16];
    unsigned short hi, lo;
#pragma unroll
    for (int t = 0; t < 8; ++t) {
      float v0 = qp[2 * t], v1 = qp[2 * t + 1];
      hi = f2bf(v0);
      unsigned short hi1 = f2bf(v1);
      u[t] = (unsigned)hi | ((unsigned)hi1 << 16);
      lo = f2bf(v0 - bf2f(hi));
      unsigned short lo1 = f2bf(v1 - bf2f(hi1));
      u[8 + t] = (unsigned)lo | ((unsigned)lo1 << 16);
    }
    uint4* dst = (uint4*)(Qcat + (size_t)r * 32);
    dst[0] = make_uint4(u[0], u[1], u[2], u[3]);
    dst[1] = make_uint4(u[4], u[5], u[6], u[7]);
    dst[2] = make_uint4(u[8], u[9], u[10], u[11]);
    dst[3] = make_uint4(u[12], u[13], u[14], u[15]);
  }
  // --- K ---
  {
    const float* kp = k + (size_t)r * 16;
    float k1[16], k2[16];
#pragma unroll
    for (int d = 0; d < 8; ++d) {
      const float kr = kp[d], ki = kp[8 + d];
      k1[d] = kr;  k1[8 + d] = -ki;
      k2[d] = ki;  k2[8 + d] = kr;
    }
    unsigned uh[8], ul[8];
#pragma unroll
    for (int t = 0; t < 8; ++t) {
      unsigned short h0 = f2bf(k1[2 * t]), h1 = f2bf(k1[2 * t + 1]);
      uh[t] = (unsigned)h0 | ((unsigned)h1 << 16);
      unsigned short l0 = f2bf(k1[2 * t] - bf2f(h0));
      unsigned short l1 = f2bf(k1[2 * t + 1] - bf2f(h1));
      ul[t] = (unsigned)l0 | ((unsigned)l1 << 16);
    }
    uint4* dh = (uint4*)(K1hi + (size_t)r * 16);
    dh[0] = make_uint4(uh[0], uh[1], uh[2], uh[3]);
    dh[1] = make_uint4(uh[4], uh[5], uh[6], uh[7]);
    uint4* dl = (uint4*)(K1loz + (size_t)r * 32);
    dl[0] = make_uint4(ul[0], ul[1], ul[2], ul[3]);
    dl[1] = make_uint4(ul[4], ul[5], ul[6], ul[7]);
    dl[2] = make_uint4(0, 0, 0, 0);
    dl[3] = make_uint4(0, 0, 0, 0);
#pragma unroll
    for (int t = 0; t < 8; ++t) {
      unsigned short h0 = f2bf(k2[2 * t]), h1 = f2bf(k2[2 * t + 1]);
      uh[t] = (unsigned)h0 | ((unsigned)h1 << 16);
      unsigned short l0 = f2bf(k2[2 * t] - bf2f(h0));
      unsigned short l1 = f2bf(k2[2 * t + 1] - bf2f(h1));
      ul[t] = (unsigned)l0 | ((unsigned)l1 << 16);
    }
    uint4* dh2 = (uint4*)(K2hi + (size_t)r * 16);
    dh2[0] = make_uint4(uh[0], uh[1], uh[2], uh[3]);
    dh2[1] = make_uint4(uh[4], uh[5], uh[6], uh[7]);
    uint4* dl2 = (uint4*)(K2loz + (size_t)r * 32);
    dl2[0] = make_uint4(ul[0], ul[1], ul[2], ul[3]);
    dl2[1] = make_uint4(ul[4], ul[5], ul[6], ul[7]);
    dl2[2] = make_uint4(0, 0, 0, 0);
    dl2[3] = make_uint4(0, 0, 0, 0);
  }
}

// ---------------------------------------------------------------------------
// Phase 2: complex V projection, bf16, CC-MAJOR: v[b][cc][l]. No LDS/barriers.
// ---------------------------------------------------------------------------
__global__ __launch_bounds__(256) void v_proj(const float* __restrict__ x,
                                              const float* __restrict__ wvT,
                                              unsigned short* __restrict__ vbf) {
  const int tid = threadIdx.x;
  const int wv  = __builtin_amdgcn_readfirstlane(tid >> 6);
  const int lt  = tid & 63;
  const int b   = blockIdx.z;
  const int c0  = blockIdx.y * 64 + wv * 16;
  const int l   = blockIdx.x * 64 + lt;
  const float* xr = x + ((size_t)(0 * Bc + b) * CGc) * Lc + l;
  const float* xi = x + ((size_t)(1 * Bc + b) * CGc) * Lc + l;
  float vr[16] = {}, vi[16] = {};
#pragma unroll 2
  for (int cin = 0; cin < CGc; ++cin) {
    const float xrv = xr[(size_t)cin * Lc];
    const float xiv = xi[(size_t)cin * Lc];
    const float* wrp = wvT + (size_t)cin * CGc + c0;
    const float* wip = wvT + (size_t)(CGc + cin) * CGc + c0;
#pragma unroll
    for (int ci = 0; ci < 16; ++ci) {
      const float wr = wrp[ci], wi = wip[ci];
      vr[ci] = fmaf(wr, xrv, vr[ci]);
      vr[ci] = fmaf(-wi, xiv, vr[ci]);
      vi[ci] = fmaf(wr, xiv, vi[ci]);
      vi[ci] = fmaf(wi, xrv, vi[ci]);
    }
  }
#pragma unroll
  for (int ci = 0; ci < 16; ++ci) {
    vbf[((size_t)b * 512 + (c0 + ci)) * Lc + l]       = f2bf(vr[ci]);
    vbf[((size_t)b * 512 + 256 + (c0 + ci)) * Lc + l] = f2bf(vi[ci]);
  }
}

// ---------------------------------------------------------------------------
// Phase 3: row max of E via MFMA split-bf16 QK^T.
// Wave = 16m strip; per 16l step: er = mfma(A,[k1lo;0], 0) then mfma(A,[k1hi;k1hi],.)
// (A = [qhi;qlo]); same for ei; e = er^2+ei^2. C layout: m=quad*4+reg, l=lane&15.
// Butterfly-max over the 16 lanes of each quad, then atomicMax (E>=0 -> uint max).
// grid (L/64, 8, B): 4 waves/block, l-split 512.
// ---------------------------------------------------------------------------
__global__ __launch_bounds__(256) void e_max(const unsigned short* __restrict__ Qcat,
                                             const unsigned short* __restrict__ K1hi,
                                             const unsigned short* __restrict__ K1loz,
                                             const unsigned short* __restrict__ K2hi,
                                             const unsigned short* __restrict__ K2loz,
                                             float* __restrict__ Mrow) {
  const int tid  = threadIdx.x;
  const int w    = tid >> 6, lane = tid & 63;
  const int lrow = lane & 15, quad = lane >> 4, qsel = quad & 1;
  const int b    = blockIdx.z;
  const int m16  = blockIdx.x * 64 + w * 16;
  const int lbeg = blockIdx.y * 512;
  const size_t kb = (size_t)b * Lc;
  const short8 afrag = *(const short8*)(Qcat + (kb + m16 + lrow) * 32 + quad * 8);
  float mx[4] = {0.f, 0.f, 0.f, 0.f};
  for (int l0 = lbeg; l0 < lbeg + 512; l0 += 16) {
    const size_t l = kb + l0 + lrow;
    const short8 b1h = *(const short8*)(K1hi + l * 16 + qsel * 8);
    const short8 b1l = *(const short8*)(K1loz + l * 32 + quad * 8);
    const short8 b2h = *(const short8*)(K2hi + l * 16 + qsel * 8);
    const short8 b2l = *(const short8*)(K2loz + l * 32 + quad * 8);
    floatx4 er = __builtin_amdgcn_mfma_f32_16x16x32_bf16(afrag, b1l, (floatx4){0.f, 0.f, 0.f, 0.f}, 0, 0, 0);
    er = __builtin_amdgcn_mfma_f32_16x16x32_bf16(afrag, b1h, er, 0, 0, 0);
    floatx4 ei = __builtin_amdgcn_mfma_f32_16x16x32_bf16(afrag, b2l, (floatx4){0.f, 0.f, 0.f, 0.f}, 0, 0, 0);
    ei = __builtin_amdgcn_mfma_f32_16x16x32_bf16(afrag, b2h, ei, 0, 0, 0);
#pragma unroll
    for (int r = 0; r < 4; ++r) {
      float e = er[r] * er[r];
      e = fmaf(ei[r], ei[r], e);
      mx[r] = fmaxf(mx[r], e);
    }
  }
#pragma unroll
  for (int r = 0; r < 4; ++r) {
    float v = mx[r];
#pragma unroll
    for (int off = 1; off < 16; off <<= 1) v = fmaxf(v, __shfl_xor(v, off));
    if (lrow == 0)
      atomicMax((unsigned*)&Mrow[kb + m16 + quad * 4 + r], __float_as_uint(v));
  }
}

// ---------------------------------------------------------------------------
// Phase 4: att[m][l] = bf16(__expf(E-M)) via the same MFMA QK^T; partial row
// sums -> atomicAdd(Ssum). Stores: each quad writes 32-B l-contiguous runs.
// ---------------------------------------------------------------------------
__global__ __launch_bounds__(256) void e_exp(const unsigned short* __restrict__ Qcat,
                                             const unsigned short* __restrict__ K1hi,
                                             const unsigned short* __restrict__ K1loz,
                                             const unsigned short* __restrict__ K2hi,
                                             const unsigned short* __restrict__ K2loz,
                                             const float* __restrict__ Mrow,
                                             unsigned short* __restrict__ att,
                                             float* __restrict__ Ssum) {
  const int tid  = threadIdx.x;
  const int w    = tid >> 6, lane = tid & 63;
  const int lrow = lane & 15, quad = lane >> 4, qsel = quad & 1;
  const int b    = blockIdx.z;
  const int m16  = blockIdx.x * 64 + w * 16;
  const int lbeg = blockIdx.y * 512;
  const size_t kb = (size_t)b * Lc;
  const short8 afrag = *(const short8*)(Qcat + (kb + m16 + lrow) * 32 + quad * 8);
  float Mv[4], sum[4] = {};
#pragma unroll
  for (int r = 0; r < 4; ++r) Mv[r] = Mrow[kb + m16 + quad * 4 + r];
  for (int l0 = lbeg; l0 < lbeg + 512; l0 += 16) {
    const size_t l = kb + l0 + lrow;
    const short8 b1h = *(const short8*)(K1hi + l * 16 + qsel * 8);
    const short8 b1l = *(const short8*)(K1loz + l * 32 + quad * 8);
    const short8 b2h = *(const short8*)(K2hi + l * 16 + qsel * 8);
    const short8 b2l = *(const short8*)(K2loz + l * 32 + quad * 8);
    floatx4 er = __builtin_amdgcn_mfma_f32_16x16x32_bf16(afrag, b1l, (floatx4){0.f, 0.f, 0.f, 0.f}, 0, 0, 0);
    er = __builtin_amdgcn_mfma_f32_16x16x32_bf16(afrag, b1h, er, 0, 0, 0);
    floatx4 ei = __builtin_amdgcn_mfma_f32_16x16x32_bf16(afrag, b2l, (floatx4){0.f, 0.f, 0.f, 0.f}, 0, 0, 0);
    ei = __builtin_amdgcn_mfma_f32_16x16x32_bf16(afrag, b2h, ei, 0, 0, 0);
#pragma unroll
    for (int r = 0; r < 4; ++r) {
      float e = er[r] * er[r];
      e = fmaf(ei[r], ei[r], e);
      const float wgt = __expf(e - Mv[r]);
      sum[r] += wgt;
      att[(kb + m16 + quad * 4 + r) * Lc + l0 + lrow] = f2bf(wgt);
    }
  }
#pragma unroll
  for (int r = 0; r < 4; ++r) {
    float v = sum[r];
#pragma unroll
    for (int off = 1; off < 16; off <<= 1) v += __shfl_xor(v, off);
    if (lrow == 0) atomicAdd(&Ssum[kb + m16 + quad * 4 + r], v);
  }
}

// ---------------------------------------------------------------------------
// Phase 5: PV GEMM via bf16 MFMA.  C[cc][m] = sum_l v[cc][l] * att[m][l].
// Tile 128cc x 64m -> 512 blocks; grid cc-fastest for att L2 reuse.
// Epilogue: out = (gamma/Ssum[m]) * acc + x.
// ---------------------------------------------------------------------------
__global__ __launch_bounds__(256) void pv_gemm(const unsigned short* __restrict__ v,
                                               const unsigned short* __restrict__ att,
                                               const float* __restrict__ Ssum,
                                               const float* __restrict__ x,
                                               const float* __restrict__ gamma,
                                               float* __restrict__ out) {
  constexpr int LDK = 72;  // 64 + 8 pad: <=2-way bank aliasing on frag reads
  __shared__ short As[128 * LDK];  // v tile   [cc][k]
  __shared__ short Bs[64 * LDK];   // att tile [m][k]
  const int tid  = threadIdx.x;
  const int b    = blockIdx.z;
  const int cc0  = blockIdx.x * 128;
  const int m0   = blockIdx.y * 64;
  const int wid  = tid >> 6, lane = tid & 63;
  const int wcc  = (wid >> 1) * 64;
  const int wm   = (wid & 1) * 32;
  const int lrow = lane & 15, quad = lane >> 4;
  floatx4 acc[4][2] = {};
  const unsigned short* vsrc = v   + ((size_t)b * 512 + cc0) * Lc;
  const unsigned short* asrc = att + ((size_t)b * Lc + m0) * Lc;
  for (int k0 = 0; k0 < Lc; k0 += 64) {
    short8 ar[4], br[2];
#pragma unroll
    for (int rnd = 0; rnd < 4; ++rnd) {
      const int idx = rnd * 256 + tid;
      const int row = idx >> 3, ch = idx & 7;
      ar[rnd] = *(const short8*)(vsrc + (size_t)row * Lc + k0 + ch * 8);
    }
#pragma unroll
    for (int rnd = 0; rnd < 2; ++rnd) {
      const int idx = rnd * 256 + tid;
      const int row = idx >> 3, ch = idx & 7;
      br[rnd] = *(const short8*)(asrc + (size_t)row * Lc + k0 + ch * 8);
    }
    __syncthreads();
#pragma unroll
    for (int rnd = 0; rnd < 4; ++rnd) {
      const int idx = rnd * 256 + tid;
      const int row = idx >> 3, ch = idx & 7;
      *(short8*)&As[row * LDK + ch * 8] = ar[rnd];
    }
#pragma unroll
    for (int rnd = 0; rnd < 2; ++rnd) {
      const int idx = rnd * 256 + tid;
      const int row = idx >> 3, ch = idx & 7;
      *(short8*)&Bs[row * LDK + ch * 8] = br[rnd];
    }
    __syncthreads();
#pragma unroll
    for (int kk = 0; kk < 64; kk += 32) {
      short8 af[4], bf[2];
#pragma unroll
      for (int i = 0; i < 4; ++i)
        af[i] = *(const short8*)&As[(wcc + i * 16 + lrow) * LDK + kk + quad * 8];
#pragma unroll
      for (int j = 0; j < 2; ++j)
        bf[j] = *(const short8*)&Bs[(wm + j * 16 + lrow) * LDK + kk + quad * 8];
#pragma unroll
      for (int i = 0; i < 4; ++i)
#pragma unroll
        for (int j = 0; j < 2; ++j)
          acc[i][j] = __builtin_amdgcn_mfma_f32_16x16x32_bf16(af[i], bf[j], acc[i][j], 0, 0, 0);
    }
  }
  const float gm = gamma[0];
  float svj[2];
#pragma unroll
  for (int j = 0; j < 2; ++j)
    svj[j] = gm / Ssum[(size_t)b * Lc + m0 + wm + j * 16 + lrow];
#pragma unroll
  for (int i = 0; i < 4; ++i) {
    const int ccb = cc0 + wcc + i * 16 + quad * 4;
#pragma unroll
    for (int j = 0; j < 2; ++j) {
      const int m = m0 + wm + j * 16 + lrow;
#pragma unroll
      for (int rg = 0; rg < 4; ++rg) {
        const int cc   = ccb + rg;
        const int comp = cc >> 8, c = cc & 255;
        const size_t idx = (((size_t)comp * Bc + b) * CGc + c) * Lc + m;
        out[idx] = svj[j] * acc[i][j][rg] + x[idx];
      }
    }
  }
}

// ---------------------------------------------------------------------------
extern "C" void kernel_launch(void* const* d_in, const int* in_sizes, int n_in,
                              void* d_out, int out_size, void* d_ws, size_t ws_size,
                              hipStream_t stream) {
  const float* x     = (const float*)d_in[0];
  const float* wq    = (const float*)d_in[1];
  const float* wk    = (const float*)d_in[2];
  const float* wv    = (const float*)d_in[3];
  const float* gamma = (const float*)d_in[4];
  float* out = (float*)d_out;

  // Workspace (~76.5 MB):
  float* q    = (float*)d_ws;                    // 2*4096*16
  float* kk   = q    + (size_t)Bc * Lc * 16;     // 2*4096*16
  float* wvT  = kk   + (size_t)Bc * Lc * 16;     // 2*256*256
  float* Mrow = wvT  + (size_t)2 * CGc * CGc;    // 2*4096   } contiguous: init
  float* Ssum = Mrow + (size_t)Bc * Lc;          // 2*4096   } zeroes both
  unsigned short* vbf   = (unsigned short*)(Ssum + (size_t)Bc * Lc);  // 2*512*4096
  unsigned short* att   = vbf + (size_t)Bc * 512 * Lc;                // 2*4096*4096
  unsigned short* Qcat  = att + (size_t)Bc * Lc * Lc;                 // 2*4096*32
  unsigned short* K1hi  = Qcat + (size_t)Bc * Lc * 32;                // 2*4096*16
  unsigned short* K1loz = K1hi + (size_t)Bc * Lc * 16;                // 2*4096*32
  unsigned short* K2hi  = K1loz + (size_t)Bc * Lc * 32;               // 2*4096*16
  unsigned short* K2loz = K2hi + (size_t)Bc * Lc * 16;                // 2*4096*32

  init_stats<<<dim3((2 * Bc * Lc) / 256), 256, 0, stream>>>(Mrow);
  wv_transpose<<<dim3((2 * CGc * CGc) / 256), 256, 0, stream>>>(wv, wvT);
  qk_proj<<<dim3(Lc / 32, Bc), 256, 0, stream>>>(x, wq, wk, q, kk);
  qk_pack<<<dim3((Bc * Lc) / 256), 256, 0, stream>>>(q, kk, Qcat, K1hi, K1loz, K2hi, K2loz);
  v_proj<<<dim3(Lc / 64, CGc / 64, Bc), 256, 0, stream>>>(x, wvT, vbf);
  e_max<<<dim3(Lc / 64, 8, Bc), 256, 0, stream>>>(Qcat, K1hi, K1loz, K2hi, K2loz, Mrow);
  e_exp<<<dim3(Lc / 64, 8, Bc), 256, 0, stream>>>(Qcat, K1hi, K1loz, K2hi, K2loz, Mrow, att, Ssum);
  pv_gemm<<<dim3(512 / 128, Lc / 64, Bc), 256, 0, stream>>>(vbf, att, Ssum, x, gamma, out);
}

// Round 8
// 214.899 us; speedup vs baseline: 5.7055x; 1.2787x over previous
//
#include <hip/hip_runtime.h>
#include <cstdint>

// Shapes (fixed by the problem): B=2, C=64, G=4 -> CG=256, DQK=8, L=64*64=4096
constexpr int Bc  = 2;
constexpr int CGc = 256;
constexpr int Dc  = 8;
constexpr int Lc  = 4096;

typedef __attribute__((ext_vector_type(8))) short short8;
typedef __attribute__((ext_vector_type(4))) float floatx4;

__device__ inline unsigned short f2bf(float f) {
  union { float f; unsigned u; } v; v.f = f;
  unsigned r = v.u + 0x7fffu + ((v.u >> 16) & 1u);
  return (unsigned short)(r >> 16);
}
__device__ inline float bf2f(unsigned short h) {
  return __uint_as_float((unsigned)h << 16);
}

// ---------------------------------------------------------------------------
// Phase -1: zero Mrow(8192) + Ssum(8192) — contiguous 16384 floats.
// ---------------------------------------------------------------------------
__global__ __launch_bounds__(256) void init_stats(float* __restrict__ p) {
  p[blockIdx.x * 256 + threadIdx.x] = 0.f;
}

// ---------------------------------------------------------------------------
// Phase 0: Wcat[cc][k] bf16 = [[Wr, -Wi], [Wi, Wr]] (512x512) for v_gemm.
// ---------------------------------------------------------------------------
__global__ __launch_bounds__(256) void wcat_pack(const float* __restrict__ wv,
                                                 unsigned short* __restrict__ Wcat) {
  const int i  = blockIdx.x * 256 + threadIdx.x;  // 0..262143
  const int cc = i >> 9, k = i & 511;
  const int co = cc >> 8, c = cc & 255, ci = k >> 8, cin = k & 255;
  const float wr = wv[(size_t)c * CGc + cin];
  const float wi = wv[(size_t)(CGc + c) * CGc + cin];
  const float val = co == 0 ? (ci == 0 ? wr : -wi) : (ci == 0 ? wi : wr);
  Wcat[i] = f2bf(val);
}

// ---------------------------------------------------------------------------
// Phase 0b: LDS-transpose x -> Xlk[b][l][cin2] bf16 (cin2 = comp*256+cin).
// ---------------------------------------------------------------------------
__global__ __launch_bounds__(256) void xT_pack(const float* __restrict__ x,
                                               unsigned short* __restrict__ Xlk) {
  __shared__ float xs[64][65];
  const int tid = threadIdx.x;
  const int b   = blockIdx.z;
  const int l0  = blockIdx.x * 64;
  const int c0  = blockIdx.y * 64;
  const int lt  = tid & 63, r4 = tid >> 6;
#pragma unroll
  for (int p = 0; p < 16; ++p) {
    const int row  = p * 4 + r4;
    const int cin2 = c0 + row;
    const int comp = cin2 >> 8, cin = cin2 & 255;
    xs[row][lt] = x[((size_t)(comp * Bc + b) * CGc + cin) * Lc + l0 + lt];
  }
  __syncthreads();
#pragma unroll
  for (int p = 0; p < 16; ++p) {
    const int lr = p * 4 + r4;
    Xlk[((size_t)b * Lc + l0 + lr) * 512 + c0 + lt] = f2bf(xs[lt][lr]);
  }
}

// ---------------------------------------------------------------------------
// Phase 1: complex Q AND K projections in one pass (x read once, fp32).
// ---------------------------------------------------------------------------
__global__ __launch_bounds__(256) void qk_proj(const float* __restrict__ x,
                                               const float* __restrict__ wq,
                                               const float* __restrict__ wk,
                                               float* __restrict__ qout,
                                               float* __restrict__ kout) {
  __shared__ float ws[4 * Dc * CGc];  // 32 KB: wq_r | wq_i | wk_r | wk_i
  const int tid = threadIdx.x;
  const int b   = blockIdx.y;
  for (int i = tid; i < 2 * Dc * CGc; i += 256) {
    ws[i]                 = wq[i];
    ws[2 * Dc * CGc + i]  = wk[i];
  }
  __syncthreads();
  const int d  = tid >> 5;   // 0..7
  const int ml = tid & 31;   // 0..31
  const int m  = blockIdx.x * 32 + ml;
  const float* xr = x + ((size_t)(0 * Bc + b) * CGc) * Lc + m;
  const float* xi = x + ((size_t)(1 * Bc + b) * CGc) * Lc + m;
  const float* wqr = ws + d * CGc;
  const float* wqi = ws + (Dc + d) * CGc;
  const float* wkr = ws + 2 * Dc * CGc + d * CGc;
  const float* wki = ws + 2 * Dc * CGc + (Dc + d) * CGc;
  float qer = 0.f, qei = 0.f, ker = 0.f, kei = 0.f;
#pragma unroll 4
  for (int cin = 0; cin < CGc; ++cin) {
    const float vr = xr[(size_t)cin * Lc];
    const float vi = xi[(size_t)cin * Lc];
    const float a1 = wqr[cin], b1 = wqi[cin];
    qer = fmaf(a1, vr, qer); qer = fmaf(-b1, vi, qer);
    qei = fmaf(a1, vi, qei); qei = fmaf(b1, vr, qei);
    const float a2 = wkr[cin], b2 = wki[cin];
    ker = fmaf(a2, vr, ker); ker = fmaf(-b2, vi, ker);
    kei = fmaf(a2, vi, kei); kei = fmaf(b2, vr, kei);
  }
  float* qp = qout + ((size_t)b * Lc + m) * 16;
  qp[d]     = qer;
  qp[8 + d] = qei;
  float* kp = kout + ((size_t)b * Lc + m) * 16;
  kp[d]     = ker;
  kp[8 + d] = kei;
}

// ---------------------------------------------------------------------------
// Phase 1b: split-bf16 packing for MFMA QK^T.
//   Qcat [r][32] = [bf16hi(q~), bf16lo(q~)]   (q~ = [qr(8), qi(8)])
//   K1hi/K1lo [r][16] for k~1=[kr,-ki];  K2hi/K2lo for k~2=[ki,kr].
// er = q~.k~1 via 2 chained MFMAs (lo dup'd across quads: extra qlo.klo term
// is ~2^-18, harmless). One thread per row r = b*L+m.
// ---------------------------------------------------------------------------
__global__ __launch_bounds__(256) void qk_pack(const float* __restrict__ q,
                                               const float* __restrict__ k,
                                               unsigned short* __restrict__ Qcat,
                                               unsigned short* __restrict__ K1hi,
                                               unsigned short* __restrict__ K1lo,
                                               unsigned short* __restrict__ K2hi,
                                               unsigned short* __restrict__ K2lo) {
  const int r = blockIdx.x * 256 + threadIdx.x;  // 0..8191
  {
    const float* qp = q + (size_t)r * 16;
    unsigned u[16];
#pragma unroll
    for (int t = 0; t < 8; ++t) {
      const float v0 = qp[2 * t], v1 = qp[2 * t + 1];
      const unsigned short h0 = f2bf(v0), h1 = f2bf(v1);
      u[t] = (unsigned)h0 | ((unsigned)h1 << 16);
      const unsigned short l0 = f2bf(v0 - bf2f(h0));
      const unsigned short l1 = f2bf(v1 - bf2f(h1));
      u[8 + t] = (unsigned)l0 | ((unsigned)l1 << 16);
    }
    uint4* dst = (uint4*)(Qcat + (size_t)r * 32);
    dst[0] = make_uint4(u[0], u[1], u[2], u[3]);
    dst[1] = make_uint4(u[4], u[5], u[6], u[7]);
    dst[2] = make_uint4(u[8], u[9], u[10], u[11]);
    dst[3] = make_uint4(u[12], u[13], u[14], u[15]);
  }
  {
    const float* kp = k + (size_t)r * 16;
    float k1[16], k2[16];
#pragma unroll
    for (int d = 0; d < 8; ++d) {
      const float kr = kp[d], ki = kp[8 + d];
      k1[d] = kr;  k1[8 + d] = -ki;
      k2[d] = ki;  k2[8 + d] = kr;
    }
    unsigned uh[8], ul[8];
#pragma unroll
    for (int t = 0; t < 8; ++t) {
      const unsigned short h0 = f2bf(k1[2 * t]), h1 = f2bf(k1[2 * t + 1]);
      uh[t] = (unsigned)h0 | ((unsigned)h1 << 16);
      const unsigned short l0 = f2bf(k1[2 * t] - bf2f(h0));
      const unsigned short l1 = f2bf(k1[2 * t + 1] - bf2f(h1));
      ul[t] = (unsigned)l0 | ((unsigned)l1 << 16);
    }
    uint4* dh = (uint4*)(K1hi + (size_t)r * 16);
    dh[0] = make_uint4(uh[0], uh[1], uh[2], uh[3]);
    dh[1] = make_uint4(uh[4], uh[5], uh[6], uh[7]);
    uint4* dl = (uint4*)(K1lo + (size_t)r * 16);
    dl[0] = make_uint4(ul[0], ul[1], ul[2], ul[3]);
    dl[1] = make_uint4(ul[4], ul[5], ul[6], ul[7]);
#pragma unroll
    for (int t = 0; t < 8; ++t) {
      const unsigned short h0 = f2bf(k2[2 * t]), h1 = f2bf(k2[2 * t + 1]);
      uh[t] = (unsigned)h0 | ((unsigned)h1 << 16);
      const unsigned short l0 = f2bf(k2[2 * t] - bf2f(h0));
      const unsigned short l1 = f2bf(k2[2 * t + 1] - bf2f(h1));
      ul[t] = (unsigned)l0 | ((unsigned)l1 << 16);
    }
    uint4* dh2 = (uint4*)(K2hi + (size_t)r * 16);
    dh2[0] = make_uint4(uh[0], uh[1], uh[2], uh[3]);
    dh2[1] = make_uint4(uh[4], uh[5], uh[6], uh[7]);
    uint4* dl2 = (uint4*)(K2lo + (size_t)r * 16);
    dl2[0] = make_uint4(ul[0], ul[1], ul[2], ul[3]);
    dl2[1] = make_uint4(ul[4], ul[5], ul[6], ul[7]);
  }
}

// ---------------------------------------------------------------------------
// Phase 2: V projection as bf16 MFMA GEMM: v[cc][l] = sum_k Wcat[cc][k]*Xlk[l][k].
// Same swizzled+pipelined structure as pv_gemm; K=512.
// ---------------------------------------------------------------------------
__global__ __launch_bounds__(256) void v_gemm(const unsigned short* __restrict__ Wcat,
                                              const unsigned short* __restrict__ Xlk,
                                              unsigned short* __restrict__ vbf) {
  __shared__ short As[128 * 64];
  __shared__ short Bs[64 * 64];
  const int tid  = threadIdx.x;
  const int b    = blockIdx.z;
  const int cc0  = blockIdx.x * 128;
  const int l0   = blockIdx.y * 64;
  const int wid  = tid >> 6, lane = tid & 63;
  const int wcc  = (wid >> 1) * 64;
  const int wl   = (wid & 1) * 32;
  const int lrow = lane & 15, quad = lane >> 4;
  floatx4 acc[4][2] = {};
  const unsigned short* wsrc = Wcat + (size_t)cc0 * 512;
  const unsigned short* xsrc = Xlk + ((size_t)b * Lc + l0) * 512;
  int s_off[4], g_off[4];
#pragma unroll
  for (int r = 0; r < 4; ++r) {
    const int idx = r * 256 + tid;
    const int row = idx >> 3, ch = idx & 7;
    s_off[r] = row * 64 + (ch ^ (row & 7)) * 8;
    g_off[r] = row * 512 + ch * 8;
  }
  short8 ar[4], br[2];
#pragma unroll
  for (int r = 0; r < 4; ++r) ar[r] = *(const short8*)(wsrc + g_off[r]);
#pragma unroll
  for (int r = 0; r < 2; ++r) br[r] = *(const short8*)(xsrc + g_off[r]);
  for (int k0 = 0; k0 < 512; k0 += 64) {
    __syncthreads();
#pragma unroll
    for (int r = 0; r < 4; ++r) *(short8*)&As[s_off[r]] = ar[r];
#pragma unroll
    for (int r = 0; r < 2; ++r) *(short8*)&Bs[s_off[r]] = br[r];
    __syncthreads();
    if (k0 + 64 < 512) {
#pragma unroll
      for (int r = 0; r < 4; ++r) ar[r] = *(const short8*)(wsrc + g_off[r] + k0 + 64);
#pragma unroll
      for (int r = 0; r < 2; ++r) br[r] = *(const short8*)(xsrc + g_off[r] + k0 + 64);
    }
#pragma unroll
    for (int kk = 0; kk < 64; kk += 32) {
      const int cb = kk >> 3;  // 0 or 4
      short8 af[4], bf[2];
#pragma unroll
      for (int i = 0; i < 4; ++i)
        af[i] = *(const short8*)&As[(wcc + i * 16 + lrow) * 64 +
                                    ((cb + quad) ^ (lrow & 7)) * 8];
#pragma unroll
      for (int j = 0; j < 2; ++j)
        bf[j] = *(const short8*)&Bs[(wl + j * 16 + lrow) * 64 +
                                    ((cb + quad) ^ (lrow & 7)) * 8];
#pragma unroll
      for (int i = 0; i < 4; ++i)
#pragma unroll
        for (int j = 0; j < 2; ++j)
          acc[i][j] = __builtin_amdgcn_mfma_f32_16x16x32_bf16(af[i], bf[j], acc[i][j], 0, 0, 0);
    }
  }
#pragma unroll
  for (int i = 0; i < 4; ++i) {
    const int ccb = cc0 + wcc + i * 16 + quad * 4;
#pragma unroll
    for (int j = 0; j < 2; ++j) {
      const int l = l0 + wl + j * 16 + lrow;
#pragma unroll
      for (int rg = 0; rg < 4; ++rg)
        vbf[((size_t)b * 512 + ccb + rg) * Lc + l] = f2bf(acc[i][j][rg]);
    }
  }
}

// ---------------------------------------------------------------------------
// Phase 3: row max of E via MFMA QK^T, hi-only (shift needs only approx max:
// error <= E*2^-8 ~ 7 -> exp <= e^7, safe; shift cancels in normalization).
// ---------------------------------------------------------------------------
__global__ __launch_bounds__(256) void e_max(const unsigned short* __restrict__ Qcat,
                                             const unsigned short* __restrict__ K1hi,
                                             const unsigned short* __restrict__ K2hi,
                                             float* __restrict__ Mrow) {
  const int tid  = threadIdx.x;
  const int w    = tid >> 6, lane = tid & 63;
  const int lrow = lane & 15, quad = lane >> 4, qsel = quad & 1;
  const int b    = blockIdx.z;
  const int m16  = blockIdx.x * 64 + w * 16;
  const int lbeg = blockIdx.y * 512;
  const size_t kb = (size_t)b * Lc;
  const short8 afrag = *(const short8*)(Qcat + (kb + m16 + lrow) * 32 + quad * 8);
  float mx[4] = {0.f, 0.f, 0.f, 0.f};
  for (int l0 = lbeg; l0 < lbeg + 512; l0 += 16) {
    const size_t l = kb + l0 + lrow;
    const short8 b1h = *(const short8*)(K1hi + l * 16 + qsel * 8);
    const short8 b2h = *(const short8*)(K2hi + l * 16 + qsel * 8);
    const floatx4 er = __builtin_amdgcn_mfma_f32_16x16x32_bf16(afrag, b1h, (floatx4){0.f, 0.f, 0.f, 0.f}, 0, 0, 0);
    const floatx4 ei = __builtin_amdgcn_mfma_f32_16x16x32_bf16(afrag, b2h, (floatx4){0.f, 0.f, 0.f, 0.f}, 0, 0, 0);
#pragma unroll
    for (int r = 0; r < 4; ++r) {
      float e = er[r] * er[r];
      e = fmaf(ei[r], ei[r], e);
      mx[r] = fmaxf(mx[r], e);
    }
  }
#pragma unroll
  for (int r = 0; r < 4; ++r) {
    float v = mx[r];
#pragma unroll
    for (int off = 1; off < 16; off <<= 1) v = fmaxf(v, __shfl_xor(v, off));
    if (lrow == 0)
      atomicMax((unsigned*)&Mrow[kb + m16 + quad * 4 + r], __float_as_uint(v));
  }
}

// ---------------------------------------------------------------------------
// Phase 4: att[m][l] = bf16(__expf(E-M)) (unnormalized), refined split-bf16 E;
// partial row sums -> atomicAdd(Ssum).
// ---------------------------------------------------------------------------
__global__ __launch_bounds__(256) void e_exp(const unsigned short* __restrict__ Qcat,
                                             const unsigned short* __restrict__ K1hi,
                                             const unsigned short* __restrict__ K1lo,
                                             const unsigned short* __restrict__ K2hi,
                                             const unsigned short* __restrict__ K2lo,
                                             const float* __restrict__ Mrow,
                                             unsigned short* __restrict__ att,
                                             float* __restrict__ Ssum) {
  const int tid  = threadIdx.x;
  const int w    = tid >> 6, lane = tid & 63;
  const int lrow = lane & 15, quad = lane >> 4, qsel = quad & 1;
  const int b    = blockIdx.z;
  const int m16  = blockIdx.x * 64 + w * 16;
  const int lbeg = blockIdx.y * 512;
  const size_t kb = (size_t)b * Lc;
  const short8 afrag = *(const short8*)(Qcat + (kb + m16 + lrow) * 32 + quad * 8);
  float Mv[4], sum[4] = {};
#pragma unroll
  for (int r = 0; r < 4; ++r) Mv[r] = Mrow[kb + m16 + quad * 4 + r];
  for (int l0 = lbeg; l0 < lbeg + 512; l0 += 16) {
    const size_t l = kb + l0 + lrow;
    const short8 b1h = *(const short8*)(K1hi + l * 16 + qsel * 8);
    const short8 b1l = *(const short8*)(K1lo + l * 16 + qsel * 8);
    const short8 b2h = *(const short8*)(K2hi + l * 16 + qsel * 8);
    const short8 b2l = *(const short8*)(K2lo + l * 16 + qsel * 8);
    floatx4 er = __builtin_amdgcn_mfma_f32_16x16x32_bf16(afrag, b1l, (floatx4){0.f, 0.f, 0.f, 0.f}, 0, 0, 0);
    er = __builtin_amdgcn_mfma_f32_16x16x32_bf16(afrag, b1h, er, 0, 0, 0);
    floatx4 ei = __builtin_amdgcn_mfma_f32_16x16x32_bf16(afrag, b2l, (floatx4){0.f, 0.f, 0.f, 0.f}, 0, 0, 0);
    ei = __builtin_amdgcn_mfma_f32_16x16x32_bf16(afrag, b2h, ei, 0, 0, 0);
#pragma unroll
    for (int r = 0; r < 4; ++r) {
      float e = er[r] * er[r];
      e = fmaf(ei[r], ei[r], e);
      const float wgt = __expf(e - Mv[r]);
      sum[r] += wgt;
      att[(kb + m16 + quad * 4 + r) * Lc + l0 + lrow] = f2bf(wgt);
    }
  }
#pragma unroll
  for (int r = 0; r < 4; ++r) {
    float v = sum[r];
#pragma unroll
    for (int off = 1; off < 16; off <<= 1) v += __shfl_xor(v, off);
    if (lrow == 0) atomicAdd(&Ssum[kb + m16 + quad * 4 + r], v);
  }
}

// ---------------------------------------------------------------------------
// Phase 5: PV GEMM, XOR-swizzled LDS (conflict-free) + register prefetch
// pipeline (next k-tile loads in flight during MFMA). Tile 128cc x 64m.
// Epilogue: out = (gamma/Ssum[m]) * acc + x.
// ---------------------------------------------------------------------------
__global__ __launch_bounds__(256) void pv_gemm(const unsigned short* __restrict__ v,
                                               const unsigned short* __restrict__ att,
                                               const float* __restrict__ Ssum,
                                               const float* __restrict__ x,
                                               const float* __restrict__ gamma,
                                               float* __restrict__ out) {
  __shared__ short As[128 * 64];
  __shared__ short Bs[64 * 64];
  const int tid  = threadIdx.x;
  const int b    = blockIdx.z;
  const int cc0  = blockIdx.x * 128;
  const int m0   = blockIdx.y * 64;
  const int wid  = tid >> 6, lane = tid & 63;
  const int wcc  = (wid >> 1) * 64;
  const int wm   = (wid & 1) * 32;
  const int lrow = lane & 15, quad = lane >> 4;
  floatx4 acc[4][2] = {};
  const unsigned short* vsrc = v   + ((size_t)b * 512 + cc0) * Lc;
  const unsigned short* asrc = att + ((size_t)b * Lc + m0) * Lc;
  int s_off[4];
  size_t g_off[4];
#pragma unroll
  for (int r = 0; r < 4; ++r) {
    const int idx = r * 256 + tid;
    const int row = idx >> 3, ch = idx & 7;
    s_off[r] = row * 64 + (ch ^ (row & 7)) * 8;
    g_off[r] = (size_t)row * Lc + ch * 8;
  }
  short8 ar[4], br[2];
#pragma unroll
  for (int r = 0; r < 4; ++r) ar[r] = *(const short8*)(vsrc + g_off[r]);
#pragma unroll
  for (int r = 0; r < 2; ++r) br[r] = *(const short8*)(asrc + g_off[r]);
  for (int k0 = 0; k0 < Lc; k0 += 64) {
    __syncthreads();
#pragma unroll
    for (int r = 0; r < 4; ++r) *(short8*)&As[s_off[r]] = ar[r];
#pragma unroll
    for (int r = 0; r < 2; ++r) *(short8*)&Bs[s_off[r]] = br[r];
    __syncthreads();
    if (k0 + 64 < Lc) {
#pragma unroll
      for (int r = 0; r < 4; ++r) ar[r] = *(const short8*)(vsrc + g_off[r] + k0 + 64);
#pragma unroll
      for (int r = 0; r < 2; ++r) br[r] = *(const short8*)(asrc + g_off[r] + k0 + 64);
    }
#pragma unroll
    for (int kk = 0; kk < 64; kk += 32) {
      const int cb = kk >> 3;  // 0 or 4
      short8 af[4], bf[2];
#pragma unroll
      for (int i = 0; i < 4; ++i)
        af[i] = *(const short8*)&As[(wcc + i * 16 + lrow) * 64 +
                                    ((cb + quad) ^ (lrow & 7)) * 8];
#pragma unroll
      for (int j = 0; j < 2; ++j)
        bf[j] = *(const short8*)&Bs[(wm + j * 16 + lrow) * 64 +
                                    ((cb + quad) ^ (lrow & 7)) * 8];
#pragma unroll
      for (int i = 0; i < 4; ++i)
#pragma unroll
        for (int j = 0; j < 2; ++j)
          acc[i][j] = __builtin_amdgcn_mfma_f32_16x16x32_bf16(af[i], bf[j], acc[i][j], 0, 0, 0);
    }
  }
  const float gm = gamma[0];
  float svj[2];
#pragma unroll
  for (int j = 0; j < 2; ++j)
    svj[j] = gm / Ssum[(size_t)b * Lc + m0 + wm + j * 16 + lrow];
#pragma unroll
  for (int i = 0; i < 4; ++i) {
    const int ccb = cc0 + wcc + i * 16 + quad * 4;
#pragma unroll
    for (int j = 0; j < 2; ++j) {
      const int m = m0 + wm + j * 16 + lrow;
#pragma unroll
      for (int rg = 0; rg < 4; ++rg) {
        const int cc   = ccb + rg;
        const int comp = cc >> 8, c = cc & 255;
        const size_t idx = (((size_t)comp * Bc + b) * CGc + c) * Lc + m;
        out[idx] = svj[j] * acc[i][j][rg] + x[idx];
      }
    }
  }
}

// ---------------------------------------------------------------------------
extern "C" void kernel_launch(void* const* d_in, const int* in_sizes, int n_in,
                              void* d_out, int out_size, void* d_ws, size_t ws_size,
                              hipStream_t stream) {
  const float* x     = (const float*)d_in[0];
  const float* wq    = (const float*)d_in[1];
  const float* wk    = (const float*)d_in[2];
  const float* wv    = (const float*)d_in[3];
  const float* gamma = (const float*)d_in[4];
  float* out = (float*)d_out;

  // Workspace (~78.7 MB). Xlk aliases att (stream-ordered: v_gemm reads Xlk
  // before e_exp overwrites the region with att).
  float* q    = (float*)d_ws;                         // 131072
  float* kk   = q    + (size_t)Bc * Lc * 16;          // 131072
  float* Mrow = kk   + (size_t)Bc * Lc * 16;          // 8192  } contiguous:
  float* Ssum = Mrow + (size_t)Bc * Lc;               // 8192  } init zeroes both
  unsigned short* vbf  = (unsigned short*)(Ssum + (size_t)Bc * Lc);  // 2*512*4096
  unsigned short* att  = vbf + (size_t)Bc * 512 * Lc;                // 2*4096*4096
  unsigned short* Xlk  = att;                                        // alias (8.4MB)
  unsigned short* Qcat = att + (size_t)Bc * Lc * Lc;                 // 8192*32
  unsigned short* K1hi = Qcat + (size_t)Bc * Lc * 32;                // 8192*16
  unsigned short* K1lo = K1hi + (size_t)Bc * Lc * 16;
  unsigned short* K2hi = K1lo + (size_t)Bc * Lc * 16;
  unsigned short* K2lo = K2hi + (size_t)Bc * Lc * 16;
  unsigned short* Wcat = K2lo + (size_t)Bc * Lc * 16;                // 512*512

  init_stats<<<dim3((2 * Bc * Lc) / 256), 256, 0, stream>>>(Mrow);
  wcat_pack<<<dim3((512 * 512) / 256), 256, 0, stream>>>(wv, Wcat);
  qk_proj<<<dim3(Lc / 32, Bc), 256, 0, stream>>>(x, wq, wk, q, kk);
  qk_pack<<<dim3((Bc * Lc) / 256), 256, 0, stream>>>(q, kk, Qcat, K1hi, K1lo, K2hi, K2lo);
  xT_pack<<<dim3(Lc / 64, 8, Bc), 256, 0, stream>>>(x, Xlk);
  v_gemm<<<dim3(512 / 128, Lc / 64, Bc), 256, 0, stream>>>(Wcat, Xlk, vbf);
  e_max<<<dim3(Lc / 64, 8, Bc), 256, 0, stream>>>(Qcat, K1hi, K2hi, Mrow);
  e_exp<<<dim3(Lc / 64, 8, Bc), 256, 0, stream>>>(Qcat, K1hi, K1lo, K2hi, K2lo, Mrow, att, Ssum);
  pv_gemm<<<dim3(512 / 128, Lc / 64, Bc), 256, 0, stream>>>(vbf, att, Ssum, x, gamma, out);
}